// Round 7
// baseline (5323.257 us; speedup 1.0000x reference)
//
#include <hip/hip_runtime.h>
#include <hip/hip_bf16.h>
#include <math.h>

typedef __hip_bfloat16 bf16;
typedef __attribute__((ext_vector_type(8))) short bf16x8;   // 8 bf16 = 4 VGPR
typedef __attribute__((ext_vector_type(4))) float f32x4;

#define NW   16384
#define LC   20
#define EDIM 64
#define HC   256
#define HW   512
#define SEQ  128
#define NOUT 50
#define NWB  64      // word-kernel blocks (2 dirs x 32), must be co-resident

__device__ __forceinline__ float sigf(float x) { return 1.0f / (1.0f + expf(-x)); }
__device__ __forceinline__ unsigned short f2bu(float f) {
  bf16 h = __float2bfloat16(f);
  return *reinterpret_cast<unsigned short*>(&h);
}
__device__ __forceinline__ bf16x8 ld8(const unsigned short* p) {
  return *reinterpret_cast<const bf16x8*>(p);
}
// Coherent (cross-XCD) plain 16B load/store: sc0 sc1 -> bypass L1+L2, hit LLC.
// Fully pipelined unlike atomic loads. Must drain with s_waitcnt before use.
__device__ __forceinline__ bf16x8 ld8sc(const unsigned short* p) {
  bf16x8 r;
  asm volatile("global_load_dwordx4 %0, %1, off sc0 sc1" : "=v"(r) : "v"(p));
  return r;
}
__device__ __forceinline__ void st8sc(unsigned short* p, bf16x8 v) {
  asm volatile("global_store_dwordx4 %0, %1, off sc0 sc1" :: "v"(p), "v"(v) : "memory");
}
#define MFMA(a, b, c) __builtin_amdgcn_mfma_f32_16x16x32_bf16(a, b, c, 0, 0, 0)

// ---------------------------------------------------------------------------
// Persistent char LSTM: 256 blocks x 64 words (1 block/CU). h in LDS
// (double-buffered, 264-short stride = 16B-aligned, 2-way banks = free),
// c in registers. Wave w covers gate-cols [w*256,+256) in 4 chunks of 64.
// Weight traffic: 640KB/block/step from L2 (halved per word vs 32-word blocks).
// ---------------------------------------------------------------------------
__global__ __launch_bounds__(256, 1) void char_lstm(
    const int* __restrict__ x, const unsigned short* __restrict__ embb,
    const unsigned short* __restrict__ Wc, const float* __restrict__ bc,
    unsigned short* __restrict__ last, const int* __restrict__ len) {
  __shared__ unsigned short Hs[2][64][264];   // 67.6 KB
  __shared__ float gt[4][64][69];             // 70.7 KB
  const int tid = threadIdx.x;
  const int w = tid >> 6, l = tid & 63;
  const int l16 = l & 15, lk8 = (l >> 4) * 8;
  const int w0 = blockIdx.x * 64;
  const int mylen = len[w0 + l];              // lane l owns word w0+l in update
  float cst[4][16];
#pragma unroll
  for (int c = 0; c < 4; ++c)
#pragma unroll
    for (int i = 0; i < 16; ++i) cst[c][i] = 0.f;

  for (int t = 0; t < LC; ++t) {
    const int cur = t & 1, nxt = cur ^ 1;
    int xi[4];
#pragma unroll
    for (int m = 0; m < 4; ++m) xi[m] = x[(w0 + m * 16 + l16) * LC + t];
#pragma unroll
    for (int c = 0; c < 4; ++c) {
      const int cc0 = w * 256 + c * 64;
      f32x4 acc[4][4] = {};
#pragma unroll
      for (int kk = 0; kk < 2; ++kk) {          // K 0..63: embedding
        const int k = kk * 32 + lk8;
        const unsigned short* wp = Wc + (size_t)(cc0 + l16) * 320 + k;
        bf16x8 bv[4];
#pragma unroll
        for (int n = 0; n < 4; ++n) bv[n] = ld8(wp + n * 16 * 320);
#pragma unroll
        for (int m = 0; m < 4; ++m) {
          bf16x8 a = ld8(embb + (size_t)xi[m] * EDIM + k);
#pragma unroll
          for (int n = 0; n < 4; ++n) acc[m][n] = MFMA(a, bv[n], acc[m][n]);
        }
      }
      if (t > 0) {
#pragma unroll
        for (int kk = 2; kk < 10; ++kk) {       // K 64..319: h(t-1) from LDS
          const int k = kk * 32 + lk8;
          const unsigned short* wp = Wc + (size_t)(cc0 + l16) * 320 + k;
          bf16x8 bv[4];
#pragma unroll
          for (int n = 0; n < 4; ++n) bv[n] = ld8(wp + n * 16 * 320);
#pragma unroll
          for (int m = 0; m < 4; ++m) {
            bf16x8 a = ld8(&Hs[cur][m * 16 + l16][k - 64]);
#pragma unroll
            for (int n = 0; n < 4; ++n) acc[m][n] = MFMA(a, bv[n], acc[m][n]);
          }
        }
      }
      const int cr = (l >> 4) * 4;
#pragma unroll
      for (int m = 0; m < 4; ++m)
#pragma unroll
        for (int n = 0; n < 4; ++n)
#pragma unroll
          for (int e = 0; e < 4; ++e)
            gt[w][m * 16 + cr + e][n * 16 + l16] = acc[m][n][e];
      // same-wave LDS RAW: lgkmcnt ordering inserted by compiler
      const int ub16 = w * 64 + c * 16;         // unit base of this chunk
      union { unsigned short s[16]; bf16x8 v[2]; } hp;
#pragma unroll
      for (int ul = 0; ul < 16; ++ul) {
        const int col = 4 * ul;
        float gi = gt[w][l][col + 0] + bc[cc0 + col + 0];
        float gf = gt[w][l][col + 1] + bc[cc0 + col + 1];
        float gg = gt[w][l][col + 2] + bc[cc0 + col + 2];
        float go = gt[w][l][col + 3] + bc[cc0 + col + 3];
        float cc = sigf(gf) * cst[c][ul] + sigf(gi) * tanhf(gg);
        cst[c][ul] = cc;
        hp.s[ul] = f2bu(sigf(go) * tanhf(cc));
      }
      *reinterpret_cast<bf16x8*>(&Hs[nxt][l][ub16]) = hp.v[0];
      *reinterpret_cast<bf16x8*>(&Hs[nxt][l][ub16 + 8]) = hp.v[1];
      if (t == mylen - 1) {
        unsigned short* lp = last + (size_t)(w0 + l) * HC + ub16;
        *reinterpret_cast<bf16x8*>(lp) = hp.v[0];
        *reinterpret_cast<bf16x8*>(lp + 8) = hp.v[1];
      } else if (mylen == 0 && t == 0) {
        unsigned short* lp = last + (size_t)(w0 + l) * HC + ub16;
        bf16x8 z = {};
        *reinterpret_cast<bf16x8*>(lp) = z;
        *reinterpret_cast<bf16x8*>(lp + 8) = z;
      }
    }
    __syncthreads();   // Hs[nxt] complete before next step reads it
  }
}

// ---------------------------------------------------------------------------
// Persistent word BiLSTM: 64 blocks (dir = bx>>5, 64 gate-cols each).
// h exchanged via sc0sc1 plain 16B loads/stores in block-contiguous layout
// hbL[buf][dir][nb][128][16] (no false sharing, full pipelining).
// hs written block-contiguously: hsL[dir][nb][b][pos][16] (plain cached).
// Fence-free per-dir spin barrier per step.
// ---------------------------------------------------------------------------
__global__ __launch_bounds__(256, 1) void word_lstm(
    const unsigned short* __restrict__ last,
    const unsigned short* __restrict__ Wf, const unsigned short* __restrict__ Wb,
    const float* __restrict__ bfi, const float* __restrict__ bbi,
    unsigned short* __restrict__ hbL,   // [2][2][32][128][16]
    unsigned short* __restrict__ hsL,   // [2][32][128][128][16]
    int* __restrict__ cnts) {           // [2][SEQ]
  __shared__ float gt[128][69];         // 35.3 KB
  const int tid = threadIdx.x;
  const int w = tid >> 6, l = tid & 63;
  const int l16 = l & 15, lk8 = (l >> 4) * 8;
  const int dir = blockIdx.x >> 5;
  const int nb = blockIdx.x & 31;
  const int c0 = nb * 64;               // gate-col base (of 2048)
  const unsigned short* W = dir ? Wb : Wf;
  const float* bias = dir ? bbi : bfi;
  const int ub = tid & 127;             // owned batch (update phase)
  const int uhi = tid >> 7;             // 0/1 -> units nb*16 + 8*uhi ..
  int* mycnt = cnts + dir * SEQ;
  float cst[8];
#pragma unroll
  for (int i = 0; i < 8; ++i) cst[i] = 0.f;

  for (int t = 0; t < SEQ; ++t) {
    const int cur = t & 1;
    const int pos = dir ? (SEQ - 1 - t) : t;
    bf16x8 af[16][2];
    if (t > 0) {                        // issue ALL h loads first (pipelined)
      const unsigned short* hp = hbL + (size_t)(((cur ^ 1) * 2 + dir) * 32) * 128 * 16;
#pragma unroll
      for (int kk = 0; kk < 16; ++kk) {
        const int u = kk * 32 + lk8;    // h unit 0..511
        const int nbs = u >> 4, ul = u & 15;
#pragma unroll
        for (int r = 0; r < 2; ++r) {
          const int bt = w * 32 + l16 + r * 16;
          af[kk][r] = ld8sc(hp + ((size_t)nbs * 128 + bt) * 16 + ul);
        }
      }
    }
    f32x4 acc[2][4] = {};
#pragma unroll
    for (int kk = 0; kk < 8; ++kk) {    // K 0..255: word_seq (plain cached)
      const int k = kk * 32 + lk8;
      bf16x8 a0 = ld8(last + ((size_t)(w * 32 + l16) * SEQ + pos) * HC + k);
      bf16x8 a1 = ld8(last + ((size_t)(w * 32 + l16 + 16) * SEQ + pos) * HC + k);
      const unsigned short* wp = W + (size_t)(c0 + l16) * 768 + k;
#pragma unroll
      for (int n = 0; n < 4; ++n) {
        bf16x8 bv = ld8(wp + n * 16 * 768);
        acc[0][n] = MFMA(a0, bv, acc[0][n]);
        acc[1][n] = MFMA(a1, bv, acc[1][n]);
      }
    }
    asm volatile("s_waitcnt vmcnt(0)" ::: "memory");
    __builtin_amdgcn_sched_barrier(0);   // rule #18: keep MFMA after the wait
    if (t > 0) {
#pragma unroll
      for (int kk = 0; kk < 16; ++kk) {  // K 256..767: h(t-1) from af regs
        const int k = 256 + kk * 32 + lk8;
        const unsigned short* wp = W + (size_t)(c0 + l16) * 768 + k;
#pragma unroll
        for (int n = 0; n < 4; ++n) {
          bf16x8 bv = ld8(wp + n * 16 * 768);
          acc[0][n] = MFMA(af[kk][0], bv, acc[0][n]);
          acc[1][n] = MFMA(af[kk][1], bv, acc[1][n]);
        }
      }
    }
    const int cr = (l >> 4) * 4;
#pragma unroll
    for (int m = 0; m < 2; ++m)
#pragma unroll
      for (int n = 0; n < 4; ++n)
#pragma unroll
        for (int e = 0; e < 4; ++e)
          gt[w * 32 + m * 16 + cr + e][n * 16 + l16] = acc[m][n][e];
    __syncthreads();
    union { unsigned short s[8]; bf16x8 v; } hv;
#pragma unroll
    for (int i = 0; i < 8; ++i) {
      const int ul = uhi * 8 + i;
      const int col = 4 * ul;
      float gi = gt[ub][col + 0] + bias[c0 + col + 0];
      float gf = gt[ub][col + 1] + bias[c0 + col + 1];
      float gg = gt[ub][col + 2] + bias[c0 + col + 2];
      float go = gt[ub][col + 3] + bias[c0 + col + 3];
      float cc = sigf(gf) * cst[i] + sigf(gi) * tanhf(gg);
      cst[i] = cc;
      hv.s[i] = f2bu(sigf(go) * tanhf(cc));
    }
    st8sc(hbL + (size_t)((cur * 2 + dir) * 32 + nb) * 128 * 16
              + (size_t)ub * 16 + uhi * 8, hv.v);
    *reinterpret_cast<bf16x8*>(
        hsL + ((size_t)((dir * 32 + nb) * 128 + ub) * 128 + pos) * 16 + uhi * 8) = hv.v;
    if (t < SEQ - 1) {
      asm volatile("s_waitcnt vmcnt(0)" ::: "memory");  // h stores at LLC
      __syncthreads();
      if (tid == 0) {
        atomicAdd(mycnt + t, 1);                        // device-scope
        while (__hip_atomic_load(mycnt + t, __ATOMIC_RELAXED,
                                 __HIP_MEMORY_SCOPE_AGENT) < NWB / 2)
          __builtin_amdgcn_s_sleep(1);
      }
      __syncthreads();
    }
  }
}

// ---------------------------------------------------------------------------
// MLP layer 1: A gathered from hsL layout. out = relu(A @ W1^T + b1).
// ---------------------------------------------------------------------------
__global__ __launch_bounds__(256) void mlp1_gemm(
    const unsigned short* __restrict__ hsL, const unsigned short* __restrict__ W1b,
    const float* __restrict__ bias, unsigned short* __restrict__ out) {
  const int tid = threadIdx.x;
  const int w = tid >> 6, l = tid & 63;
  const int l16 = l & 15, lk8 = (l >> 4) * 8;
  const int row0 = blockIdx.y * 128 + w * 32;
  const int col0 = blockIdx.x * 64;
  f32x4 acc[2][4] = {};
  for (int kk = 0; kk < 32; ++kk) {
    const int k = kk * 32 + lk8;               // 0..1023
    const int dirk = k >> 9, u = k & 511, nbs = u >> 4, ul = u & 15;
    const int r0 = row0 + l16, r1 = r0 + 16;
    bf16x8 a0 = ld8(hsL + (((size_t)(dirk * 32 + nbs) * 128 + (r0 >> 7)) * 128
                           + (r0 & 127)) * 16 + ul);
    bf16x8 a1 = ld8(hsL + (((size_t)(dirk * 32 + nbs) * 128 + (r1 >> 7)) * 128
                           + (r1 & 127)) * 16 + ul);
    const unsigned short* wp = W1b + (size_t)(col0 + l16) * 1024 + k;
#pragma unroll
    for (int n = 0; n < 4; ++n) {
      bf16x8 bv = ld8(wp + n * 16 * 1024);
      acc[0][n] = MFMA(a0, bv, acc[0][n]);
      acc[1][n] = MFMA(a1, bv, acc[1][n]);
    }
  }
  const int cr = (l >> 4) * 4;
#pragma unroll
  for (int m = 0; m < 2; ++m)
#pragma unroll
    for (int n = 0; n < 4; ++n)
#pragma unroll
      for (int e = 0; e < 4; ++e) {
        const int r = row0 + m * 16 + cr + e;
        const int c = col0 + n * 16 + l16;
        out[(size_t)r * 256 + c] = f2bu(fmaxf(acc[m][n][e] + bias[c], 0.f));
      }
}

// ---------------------------------------------------------------------------
// MLP layer 2 (row-major A): out = relu(A @ W2^T + b2).
// ---------------------------------------------------------------------------
__global__ __launch_bounds__(256) void mlp_gemm(
    const unsigned short* __restrict__ A, int lda,
    const unsigned short* __restrict__ W, int ldw,
    const float* __restrict__ bias, unsigned short* __restrict__ out,
    int ldo, int nk, int relu) {
  const int tid = threadIdx.x;
  const int w = tid >> 6, l = tid & 63;
  const int l16 = l & 15, lk8 = (l >> 4) * 8;
  const int row0 = blockIdx.y * 128 + w * 32;
  const int col0 = blockIdx.x * 64;
  f32x4 acc[2][4] = {};
  for (int kk = 0; kk < nk; ++kk) {
    const int k = kk * 32 + lk8;
    bf16x8 a0 = ld8(A + (size_t)(row0 + l16) * lda + k);
    bf16x8 a1 = ld8(A + (size_t)(row0 + 16 + l16) * lda + k);
    const unsigned short* wp = W + (size_t)(col0 + l16) * ldw + k;
    bf16x8 bb[4];
#pragma unroll
    for (int n = 0; n < 4; ++n) bb[n] = ld8(wp + n * 16 * ldw);
#pragma unroll
    for (int n = 0; n < 4; ++n) {
      acc[0][n] = MFMA(a0, bb[n], acc[0][n]);
      acc[1][n] = MFMA(a1, bb[n], acc[1][n]);
    }
  }
  const int cr = (l >> 4) * 4;
#pragma unroll
  for (int m = 0; m < 2; ++m)
#pragma unroll
    for (int n = 0; n < 4; ++n)
#pragma unroll
      for (int e = 0; e < 4; ++e) {
        const int r = row0 + m * 16 + cr + e;
        const int c = col0 + n * 16 + l16;
        float v = acc[m][n][e] + bias[c];
        if (relu) v = fmaxf(v, 0.f);
        out[(size_t)r * ldo + c] = f2bu(v);
      }
}

// ---------------------------------------------------------------------------
// Logits (MFMA, N=64 padded) + log_softmax over 50, fused. 128 rows/block.
// ---------------------------------------------------------------------------
__global__ __launch_bounds__(256) void logits_fused(
    const unsigned short* __restrict__ h2, const unsigned short* __restrict__ W3p,
    const float* __restrict__ b3, float* __restrict__ out) {
  __shared__ float gt[128][68];
  __shared__ float lseb[128];
  const int tid = threadIdx.x;
  const int w = tid >> 6, l = tid & 63;
  const int l16 = l & 15, lk8 = (l >> 4) * 8;
  const int r0 = blockIdx.x * 128;
  const int rr0 = w * 32 + l16, rr1 = rr0 + 16;
  f32x4 acc[2][4] = {};
#pragma unroll
  for (int kk = 0; kk < 8; ++kk) {
    const int k = kk * 32 + lk8;
    bf16x8 a0 = ld8(h2 + (size_t)(r0 + rr0) * 256 + k);
    bf16x8 a1 = ld8(h2 + (size_t)(r0 + rr1) * 256 + k);
#pragma unroll
    for (int n = 0; n < 4; ++n) {
      bf16x8 bv = ld8(W3p + (size_t)(n * 16 + l16) * 256 + k);
      acc[0][n] = MFMA(a0, bv, acc[0][n]);
      acc[1][n] = MFMA(a1, bv, acc[1][n]);
    }
  }
  const int cr = (l >> 4) * 4;
#pragma unroll
  for (int m = 0; m < 2; ++m)
#pragma unroll
    for (int n = 0; n < 4; ++n)
#pragma unroll
      for (int e = 0; e < 4; ++e) {
        const int col = n * 16 + l16;
        gt[w * 32 + m * 16 + cr + e][col] =
            acc[m][n][e] + (col < NOUT ? b3[col] : 0.f);
      }
  __syncthreads();
  if (tid < 128) {
    float mx = -INFINITY;
#pragma unroll
    for (int j = 0; j < NOUT; ++j) mx = fmaxf(mx, gt[tid][j]);
    float s = 0.f;
#pragma unroll
    for (int j = 0; j < NOUT; ++j) s += expf(gt[tid][j] - mx);
    lseb[tid] = logf(s) + mx;
  }
  __syncthreads();
  for (int idx = tid; idx < 128 * NOUT; idx += 256) {
    const int r = idx / NOUT, j = idx - r * NOUT;
    out[(size_t)(r0 + r) * NOUT + j] = gt[r][j] - lseb[r];
  }
}

// ---------------------------------------------------------------------------
// Prep kernels
// ---------------------------------------------------------------------------
__global__ void prep_w(const float* __restrict__ ih, const float* __restrict__ hh,
                       unsigned short* __restrict__ dst, int HU, int KI, int KH) {
  const int K = KI + KH;
  const long tot = (long)HU * 4 * K;
  for (long idx = (long)blockIdx.x * blockDim.x + threadIdx.x; idx < tot;
       idx += (long)gridDim.x * blockDim.x) {
    const int row = (int)(idx / K), k = (int)(idx % K);
    const int u = row >> 2, g = row & 3;
    const float v = (k < KI) ? ih[(size_t)(g * HU + u) * KI + k]
                             : hh[(size_t)(g * HU + u) * KH + (k - KI)];
    dst[idx] = f2bu(v);
  }
}

__global__ void prep_bias(const float* bih, const float* bhh, float* dst, int HU) {
  const int idx = blockIdx.x * blockDim.x + threadIdx.x;
  if (idx < 4 * HU) {
    const int u = idx >> 2, g = idx & 3;
    dst[idx] = bih[g * HU + u] + bhh[g * HU + u];
  }
}

__global__ void conv_bf(const float* __restrict__ src, unsigned short* __restrict__ dst,
                        long n) {
  for (long i = (long)blockIdx.x * blockDim.x + threadIdx.x; i < n;
       i += (long)gridDim.x * blockDim.x)
    dst[i] = f2bu(src[i]);
}

__global__ void prep_w3(const float* __restrict__ W3, unsigned short* __restrict__ dst) {
  const int i = blockIdx.x * blockDim.x + threadIdx.x;   // 64*256
  if (i < 64 * 256) {
    const int r = i >> 8;
    dst[i] = (r < NOUT) ? f2bu(W3[i]) : 0;
  }
}

__global__ void lengths_k(const int* x, int* len) {
  const int n = blockIdx.x * blockDim.x + threadIdx.x;
  if (n < NW) {
    int c = 0;
#pragma unroll
    for (int l = 0; l < LC; ++l) c += (x[(size_t)n * LC + l] != 0) ? 1 : 0;
    len[n] = c;
  }
}

__global__ void zero_cnts(int* cnts) {
  if (threadIdx.x < 256) cnts[threadIdx.x] = 0;
}

__global__ void sentinel_k(float* out, int n) {
  const int i = blockIdx.x * blockDim.x + threadIdx.x;
  if (i < n) out[i] = 1000.0f;
}

// ---------------------------------------------------------------------------
extern "C" void kernel_launch(void* const* d_in, const int* in_sizes, int n_in,
                              void* d_out, int out_size, void* d_ws, size_t ws_size,
                              hipStream_t stream) {
  const int*   x     = (const int*)d_in[0];
  const float* emb   = (const float*)d_in[1];
  const float* cW_ih = (const float*)d_in[2];
  const float* cW_hh = (const float*)d_in[3];
  const float* cb_ih = (const float*)d_in[4];
  const float* cb_hh = (const float*)d_in[5];
  const float* fW_ih = (const float*)d_in[6];
  const float* fW_hh = (const float*)d_in[7];
  const float* fb_ih = (const float*)d_in[8];
  const float* fb_hh = (const float*)d_in[9];
  const float* bW_ih = (const float*)d_in[10];
  const float* bW_hh = (const float*)d_in[11];
  const float* bb_ih = (const float*)d_in[12];
  const float* bb_hh = (const float*)d_in[13];
  const float* W1 = (const float*)d_in[14];
  const float* b1 = (const float*)d_in[15];
  const float* W2 = (const float*)d_in[16];
  const float* b2 = (const float*)d_in[17];
  const float* W3 = (const float*)d_in[18];
  const float* b3 = (const float*)d_in[19];
  float* out = (float*)d_out;
  (void)in_sizes; (void)n_in;

  char* ws = (char*)d_ws;
  size_t off = 0;
  auto alloc = [&](size_t bytes) -> char* {
    char* p = ws + off;
    off += (bytes + 255) & ~(size_t)255;
    return p;
  };
  int*            len_ = (int*)alloc((size_t)NW * 4);
  int*            cnts = (int*)alloc(2 * SEQ * 4);
  unsigned short* embb = (unsigned short*)alloc((size_t)100 * EDIM * 2);
  unsigned short* Wc_i = (unsigned short*)alloc((size_t)1024 * 320 * 2);
  unsigned short* Wf_i = (unsigned short*)alloc((size_t)2048 * 768 * 2);
  unsigned short* Wb_i = (unsigned short*)alloc((size_t)2048 * 768 * 2);
  unsigned short* W1b  = (unsigned short*)alloc((size_t)256 * 1024 * 2);
  unsigned short* W2b  = (unsigned short*)alloc((size_t)256 * 256 * 2);
  unsigned short* W3p  = (unsigned short*)alloc((size_t)64 * 256 * 2);
  float*          bc_i = (float*)alloc(1024 * 4);
  float*          bf_i = (float*)alloc(2048 * 4);
  float*          bb_i = (float*)alloc(2048 * 4);
  unsigned short* last = (unsigned short*)alloc((size_t)NW * HC * 2);        // 8MB
  unsigned short* hbL  = (unsigned short*)alloc((size_t)2 * 2 * 32 * 128 * 16 * 2);
  unsigned short* hsL  = (unsigned short*)alloc((size_t)2 * 32 * 128 * 128 * 16 * 2);
  unsigned short* h1   = (unsigned short*)alloc((size_t)NW * HC * 2);        // 8MB
  unsigned short* h2   = (unsigned short*)alloc((size_t)NW * HC * 2);        // 8MB

  if (off > ws_size) {
    sentinel_k<<<(out_size + 255) / 256, 256, 0, stream>>>(out, out_size);
    return;
  }

  auto cdiv = [](long a, long b) { return (int)((a + b - 1) / b); };

  // ---- prep ----
  prep_w<<<1280, 256, 0, stream>>>(cW_ih, cW_hh, Wc_i, HC, EDIM, HC);
  prep_w<<<3072, 256, 0, stream>>>(fW_ih, fW_hh, Wf_i, HW, HC, HW);
  prep_w<<<3072, 256, 0, stream>>>(bW_ih, bW_hh, Wb_i, HW, HC, HW);
  prep_bias<<<cdiv(1024, 256), 256, 0, stream>>>(cb_ih, cb_hh, bc_i, HC);
  prep_bias<<<cdiv(2048, 256), 256, 0, stream>>>(fb_ih, fb_hh, bf_i, HW);
  prep_bias<<<cdiv(2048, 256), 256, 0, stream>>>(bb_ih, bb_hh, bb_i, HW);
  conv_bf<<<25, 256, 0, stream>>>(emb, embb, 100L * EDIM);
  conv_bf<<<1024, 256, 0, stream>>>(W1, W1b, 256L * 1024);
  conv_bf<<<256, 256, 0, stream>>>(W2, W2b, 256L * 256);
  prep_w3<<<64, 256, 0, stream>>>(W3, W3p);
  lengths_k<<<cdiv(NW, 256), 256, 0, stream>>>(x, len_);
  zero_cnts<<<1, 256, 0, stream>>>(cnts);

  // ---- persistent char LSTM (1 launch, 1 block/CU) ----
  char_lstm<<<NW / 64, 256, 0, stream>>>(x, embb, Wc_i, bc_i, last, len_);

  // ---- persistent word BiLSTM (1 launch, fence-free barriers) ----
  word_lstm<<<NWB, 256, 0, stream>>>(last, Wf_i, Wb_i, bf_i, bb_i, hbL, hsL, cnts);

  // ---- MLP + fused logits/log_softmax ----
  mlp1_gemm<<<dim3(4, 128), 256, 0, stream>>>(hsL, W1b, b1, h1);
  mlp_gemm<<<dim3(4, 128), 256, 0, stream>>>(h1, 256, W2b, 256, b2, h2, 256, 8, 1);
  logits_fused<<<NW / 128, 256, 0, stream>>>(h2, W3p, b3, out);
}

// Round 8
// 3389.145 us; speedup vs baseline: 1.5707x; 1.5707x over previous
//
#include <hip/hip_runtime.h>
#include <hip/hip_bf16.h>
#include <math.h>

typedef __hip_bfloat16 bf16;
typedef __attribute__((ext_vector_type(8))) short bf16x8;   // 8 bf16 = 4 VGPR
typedef __attribute__((ext_vector_type(4))) float f32x4;

#define NW   16384
#define LC   20
#define EDIM 64
#define HC   256
#define HW   512
#define SEQ  128
#define NOUT 50
#define NWB  64      // word-kernel blocks (2 dirs x 32), must be co-resident

__device__ __forceinline__ float sigf(float x) { return 1.0f / (1.0f + expf(-x)); }
__device__ __forceinline__ unsigned short f2bu(float f) {
  bf16 h = __float2bfloat16(f);
  return *reinterpret_cast<unsigned short*>(&h);
}
__device__ __forceinline__ bf16x8 ld8(const unsigned short* p) {
  return *reinterpret_cast<const bf16x8*>(p);
}
// Coherent (cross-XCD) plain 16B load/store: sc0 sc1 -> bypass L1+L2, hit LLC.
__device__ __forceinline__ bf16x8 ld8sc(const unsigned short* p) {
  bf16x8 r;
  asm volatile("global_load_dwordx4 %0, %1, off sc0 sc1" : "=v"(r) : "v"(p));
  return r;
}
__device__ __forceinline__ void st8sc(unsigned short* p, bf16x8 v) {
  asm volatile("global_store_dwordx4 %0, %1, off sc0 sc1" :: "v"(p), "v"(v) : "memory");
}
#define MFMA(a, b, c) __builtin_amdgcn_mfma_f32_16x16x32_bf16(a, b, c, 0, 0, 0)

// ---------------------------------------------------------------------------
// Persistent char LSTM (r6-proven geometry): 512 blocks x 32 words. h in LDS
// (double-buffered), c in registers (cst[4][8], no spill pressure).
// Writes last hidden state TIME-MAJOR: lastT[pos][b][HC], word n = b*SEQ+pos.
// ---------------------------------------------------------------------------
__global__ __launch_bounds__(256) void char_lstm(
    const int* __restrict__ x, const unsigned short* __restrict__ embb,
    const unsigned short* __restrict__ Wc, const float* __restrict__ bc,
    unsigned short* __restrict__ lastT, const int* __restrict__ len) {
  __shared__ unsigned short Hs[2][32][264];   // 33.8 KB
  __shared__ float gt[4][32][68];             // 34.8 KB
  const int tid = threadIdx.x;
  const int w = tid >> 6, l = tid & 63;
  const int l16 = l & 15, lk8 = (l >> 4) * 8;
  const int hi = l >> 5;              // 0/1
  const int wl = l & 31;              // owned word (update phase)
  const int w0 = blockIdx.x * 32;
  const int mylen = len[w0 + wl];
  const int n = w0 + wl;
  const size_t lrow = (size_t)((n & 127) * 128 + (n >> 7)) * HC;  // time-major row
  float cst[4][8];
#pragma unroll
  for (int c = 0; c < 4; ++c)
#pragma unroll
    for (int i = 0; i < 8; ++i) cst[c][i] = 0.f;

  for (int t = 0; t < LC; ++t) {
    const int cur = t & 1, nxt = cur ^ 1;
    const int xi0 = x[(w0 + l16) * LC + t];
    const int xi1 = x[(w0 + 16 + l16) * LC + t];
#pragma unroll
    for (int c = 0; c < 4; ++c) {
      const int cc0 = w * 256 + c * 64;
      f32x4 acc[2][4] = {};
#pragma unroll
      for (int kk = 0; kk < 2; ++kk) {          // K 0..63: embedding
        const int k = kk * 32 + lk8;
        bf16x8 a0 = ld8(embb + (size_t)xi0 * EDIM + k);
        bf16x8 a1 = ld8(embb + (size_t)xi1 * EDIM + k);
        const unsigned short* wp = Wc + (size_t)(cc0 + l16) * 320 + k;
#pragma unroll
        for (int nn = 0; nn < 4; ++nn) {
          bf16x8 bv = ld8(wp + nn * 16 * 320);
          acc[0][nn] = MFMA(a0, bv, acc[0][nn]);
          acc[1][nn] = MFMA(a1, bv, acc[1][nn]);
        }
      }
      if (t > 0) {
#pragma unroll
        for (int kk = 2; kk < 10; ++kk) {       // K 64..319: h(t-1) from LDS
          const int k = kk * 32 + lk8;
          bf16x8 a0 = ld8(&Hs[cur][l16][k - 64]);
          bf16x8 a1 = ld8(&Hs[cur][16 + l16][k - 64]);
          const unsigned short* wp = Wc + (size_t)(cc0 + l16) * 320 + k;
#pragma unroll
          for (int nn = 0; nn < 4; ++nn) {
            bf16x8 bv = ld8(wp + nn * 16 * 320);
            acc[0][nn] = MFMA(a0, bv, acc[0][nn]);
            acc[1][nn] = MFMA(a1, bv, acc[1][nn]);
          }
        }
      }
      const int cr = (l >> 4) * 4;
#pragma unroll
      for (int m = 0; m < 2; ++m)
#pragma unroll
        for (int nn = 0; nn < 4; ++nn)
#pragma unroll
          for (int e = 0; e < 4; ++e)
            gt[w][m * 16 + cr + e][nn * 16 + l16] = acc[m][nn][e];
      // same-wave LDS RAW: compiler inserts lgkmcnt waits
#pragma unroll
      for (int i = 0; i < 8; ++i) {
        const int ul = 2 * i + hi;              // unit-local 0..15
        const int col = 4 * ul;
        float gi = gt[w][wl][col + 0] + bc[cc0 + col + 0];
        float gf = gt[w][wl][col + 1] + bc[cc0 + col + 1];
        float gg = gt[w][wl][col + 2] + bc[cc0 + col + 2];
        float go = gt[w][wl][col + 3] + bc[cc0 + col + 3];
        float cc = sigf(gf) * cst[c][i] + sigf(gi) * tanhf(gg);
        cst[c][i] = cc;
        float h = sigf(go) * tanhf(cc);
        const int unit = (cc0 >> 2) + ul;
        Hs[nxt][wl][unit] = f2bu(h);
        if (t == mylen - 1)
          lastT[lrow + unit] = f2bu(h);
        else if (mylen == 0 && t == 0)
          lastT[lrow + unit] = 0;               // bf16 +0
      }
    }
    __syncthreads();   // Hs[nxt] complete before next step reads it
  }
}

// ---------------------------------------------------------------------------
// Persistent word BiLSTM: 64 blocks (dir = bx>>5, 64 gate-cols each).
// Flag barrier (per-block arrive words, wave-0 ballot poll, no atomics on a
// shared line), overlapped with the h-independent x-part MFMA.
// h exchange via sc0sc1 16B ops in hbL[buf][dir][nb][128][16].
// ---------------------------------------------------------------------------
__global__ __launch_bounds__(256, 1) void word_lstm(
    const unsigned short* __restrict__ lastT,   // [pos][128][HC]
    const unsigned short* __restrict__ Wf, const unsigned short* __restrict__ Wb,
    const float* __restrict__ bfi, const float* __restrict__ bbi,
    unsigned short* __restrict__ hbL,   // [2][2][32][128][16]
    unsigned short* __restrict__ hsL,   // [2][32][128][128][16]
    int* __restrict__ aflag) {          // [2][SEQ][32]
  __shared__ float gt[128][69];         // 35.3 KB
  const int tid = threadIdx.x;
  const int w = tid >> 6, l = tid & 63;
  const int l16 = l & 15, lk8 = (l >> 4) * 8;
  const int dir = blockIdx.x >> 5;
  const int nb = blockIdx.x & 31;
  const int c0 = nb * 64;               // gate-col base (of 2048)
  const unsigned short* W = dir ? Wb : Wf;
  const float* bias = dir ? bbi : bfi;
  const int ub = tid & 127;             // owned batch (update phase)
  const int uhi = tid >> 7;             // 0/1 -> units nb*16 + 8*uhi ..
  float cst[8];
#pragma unroll
  for (int i = 0; i < 8; ++i) cst[i] = 0.f;

  for (int t = 0; t < SEQ; ++t) {
    const int cur = t & 1;
    const int pos = dir ? (SEQ - 1 - t) : t;
    // ---- x-part: contiguous lastT slab, independent of h ----
    f32x4 acc[2][4] = {};
#pragma unroll
    for (int kk = 0; kk < 8; ++kk) {
      const int k = kk * 32 + lk8;
      bf16x8 a0 = ld8(lastT + ((size_t)pos * 128 + w * 32 + l16) * HC + k);
      bf16x8 a1 = ld8(lastT + ((size_t)pos * 128 + w * 32 + l16 + 16) * HC + k);
      const unsigned short* wp = W + (size_t)(c0 + l16) * 768 + k;
#pragma unroll
      for (int nn = 0; nn < 4; ++nn) {
        bf16x8 bv = ld8(wp + nn * 16 * 768);
        acc[0][nn] = MFMA(a0, bv, acc[0][nn]);
        acc[1][nn] = MFMA(a1, bv, acc[1][nn]);
      }
    }
    if (t > 0) {
      // ---- flag-barrier wait for step t-1 (overlapped with x-part above) ----
      if (w == 0) {
        const int* fp = aflag + (dir * SEQ + (t - 1)) * 32;
        for (;;) {
          int v = 1;
          if (l < 32)
            v = __hip_atomic_load(fp + l, __ATOMIC_RELAXED,
                                  __HIP_MEMORY_SCOPE_AGENT);
          if (__ballot(v != 0) == ~0ull) break;
          __builtin_amdgcn_s_sleep(1);
        }
      }
      __syncthreads();
      // ---- h loads (coherent) + h-part MFMA ----
      bf16x8 af[16][2];
      const unsigned short* hp =
          hbL + (size_t)(((cur ^ 1) * 2 + dir) * 32) * 128 * 16;
#pragma unroll
      for (int kk = 0; kk < 16; ++kk) {
        const int u = kk * 32 + lk8;
        const int nbs = u >> 4, ul = u & 15;
#pragma unroll
        for (int r = 0; r < 2; ++r) {
          const int bt = w * 32 + l16 + r * 16;
          af[kk][r] = ld8sc(hp + ((size_t)nbs * 128 + bt) * 16 + ul);
        }
      }
      asm volatile("s_waitcnt vmcnt(0)" ::: "memory");
      __builtin_amdgcn_sched_barrier(0);   // rule #18: MFMA stays after wait
#pragma unroll
      for (int kk = 0; kk < 16; ++kk) {
        const int k = 256 + kk * 32 + lk8;
        const unsigned short* wp = W + (size_t)(c0 + l16) * 768 + k;
#pragma unroll
        for (int nn = 0; nn < 4; ++nn) {
          bf16x8 bv = ld8(wp + nn * 16 * 768);
          acc[0][nn] = MFMA(af[kk][0], bv, acc[0][nn]);
          acc[1][nn] = MFMA(af[kk][1], bv, acc[1][nn]);
        }
      }
    }
    const int cr = (l >> 4) * 4;
#pragma unroll
    for (int m = 0; m < 2; ++m)
#pragma unroll
      for (int nn = 0; nn < 4; ++nn)
#pragma unroll
        for (int e = 0; e < 4; ++e)
          gt[w * 32 + m * 16 + cr + e][nn * 16 + l16] = acc[m][nn][e];
    __syncthreads();
    union { unsigned short s[8]; bf16x8 v; } hv;
#pragma unroll
    for (int i = 0; i < 8; ++i) {
      const int ul = uhi * 8 + i;
      const int col = 4 * ul;
      float gi = gt[ub][col + 0] + bias[c0 + col + 0];
      float gf = gt[ub][col + 1] + bias[c0 + col + 1];
      float gg = gt[ub][col + 2] + bias[c0 + col + 2];
      float go = gt[ub][col + 3] + bias[c0 + col + 3];
      float cc = sigf(gf) * cst[i] + sigf(gi) * tanhf(gg);
      cst[i] = cc;
      hv.s[i] = f2bu(sigf(go) * tanhf(cc));
    }
    st8sc(hbL + (size_t)((cur * 2 + dir) * 32 + nb) * 128 * 16
              + (size_t)ub * 16 + uhi * 8, hv.v);
    *reinterpret_cast<bf16x8*>(
        hsL + ((size_t)((dir * 32 + nb) * 128 + ub) * 128 + pos) * 16 + uhi * 8) = hv.v;
    if (t < SEQ - 1) {
      asm volatile("s_waitcnt vmcnt(0)" ::: "memory");  // h at LLC
      __syncthreads();                                   // all waves drained
      if (tid == 0)
        __hip_atomic_store(aflag + (dir * SEQ + t) * 32 + nb, 1,
                           __ATOMIC_RELAXED, __HIP_MEMORY_SCOPE_AGENT);
    }
  }
}

// ---------------------------------------------------------------------------
// MLP layer 1: A gathered from hsL layout. out = relu(A @ W1^T + b1).
// ---------------------------------------------------------------------------
__global__ __launch_bounds__(256) void mlp1_gemm(
    const unsigned short* __restrict__ hsL, const unsigned short* __restrict__ W1b,
    const float* __restrict__ bias, unsigned short* __restrict__ out) {
  const int tid = threadIdx.x;
  const int w = tid >> 6, l = tid & 63;
  const int l16 = l & 15, lk8 = (l >> 4) * 8;
  const int row0 = blockIdx.y * 128 + w * 32;
  const int col0 = blockIdx.x * 64;
  f32x4 acc[2][4] = {};
  for (int kk = 0; kk < 32; ++kk) {
    const int k = kk * 32 + lk8;               // 0..1023
    const int dirk = k >> 9, u = k & 511, nbs = u >> 4, ul = u & 15;
    const int r0 = row0 + l16, r1 = r0 + 16;
    bf16x8 a0 = ld8(hsL + (((size_t)(dirk * 32 + nbs) * 128 + (r0 >> 7)) * 128
                           + (r0 & 127)) * 16 + ul);
    bf16x8 a1 = ld8(hsL + (((size_t)(dirk * 32 + nbs) * 128 + (r1 >> 7)) * 128
                           + (r1 & 127)) * 16 + ul);
    const unsigned short* wp = W1b + (size_t)(col0 + l16) * 1024 + k;
#pragma unroll
    for (int nn = 0; nn < 4; ++nn) {
      bf16x8 bv = ld8(wp + nn * 16 * 1024);
      acc[0][nn] = MFMA(a0, bv, acc[0][nn]);
      acc[1][nn] = MFMA(a1, bv, acc[1][nn]);
    }
  }
  const int cr = (l >> 4) * 4;
#pragma unroll
  for (int m = 0; m < 2; ++m)
#pragma unroll
    for (int nn = 0; nn < 4; ++nn)
#pragma unroll
      for (int e = 0; e < 4; ++e) {
        const int r = row0 + m * 16 + cr + e;
        const int c = col0 + nn * 16 + l16;
        out[(size_t)r * 256 + c] = f2bu(fmaxf(acc[m][nn][e] + bias[c], 0.f));
      }
}

// ---------------------------------------------------------------------------
// MLP layer 2 (row-major A): out = relu(A @ W2^T + b2).
// ---------------------------------------------------------------------------
__global__ __launch_bounds__(256) void mlp_gemm(
    const unsigned short* __restrict__ A, int lda,
    const unsigned short* __restrict__ W, int ldw,
    const float* __restrict__ bias, unsigned short* __restrict__ out,
    int ldo, int nk, int relu) {
  const int tid = threadIdx.x;
  const int w = tid >> 6, l = tid & 63;
  const int l16 = l & 15, lk8 = (l >> 4) * 8;
  const int row0 = blockIdx.y * 128 + w * 32;
  const int col0 = blockIdx.x * 64;
  f32x4 acc[2][4] = {};
  for (int kk = 0; kk < nk; ++kk) {
    const int k = kk * 32 + lk8;
    bf16x8 a0 = ld8(A + (size_t)(row0 + l16) * lda + k);
    bf16x8 a1 = ld8(A + (size_t)(row0 + 16 + l16) * lda + k);
    const unsigned short* wp = W + (size_t)(col0 + l16) * ldw + k;
    bf16x8 bb[4];
#pragma unroll
    for (int nn = 0; nn < 4; ++nn) bb[nn] = ld8(wp + nn * 16 * ldw);
#pragma unroll
    for (int nn = 0; nn < 4; ++nn) {
      acc[0][nn] = MFMA(a0, bb[nn], acc[0][nn]);
      acc[1][nn] = MFMA(a1, bb[nn], acc[1][nn]);
    }
  }
  const int cr = (l >> 4) * 4;
#pragma unroll
  for (int m = 0; m < 2; ++m)
#pragma unroll
    for (int nn = 0; nn < 4; ++nn)
#pragma unroll
      for (int e = 0; e < 4; ++e) {
        const int r = row0 + m * 16 + cr + e;
        const int c = col0 + nn * 16 + l16;
        float v = acc[m][nn][e] + bias[c];
        if (relu) v = fmaxf(v, 0.f);
        out[(size_t)r * ldo + c] = f2bu(v);
      }
}

// ---------------------------------------------------------------------------
// Logits (MFMA, N=64 padded) + log_softmax over 50, fused. 128 rows/block.
// ---------------------------------------------------------------------------
__global__ __launch_bounds__(256) void logits_fused(
    const unsigned short* __restrict__ h2, const unsigned short* __restrict__ W3p,
    const float* __restrict__ b3, float* __restrict__ out) {
  __shared__ float gt[128][68];
  __shared__ float lseb[128];
  const int tid = threadIdx.x;
  const int w = tid >> 6, l = tid & 63;
  const int l16 = l & 15, lk8 = (l >> 4) * 8;
  const int r0 = blockIdx.x * 128;
  const int rr0 = w * 32 + l16, rr1 = rr0 + 16;
  f32x4 acc[2][4] = {};
#pragma unroll
  for (int kk = 0; kk < 8; ++kk) {
    const int k = kk * 32 + lk8;
    bf16x8 a0 = ld8(h2 + (size_t)(r0 + rr0) * 256 + k);
    bf16x8 a1 = ld8(h2 + (size_t)(r0 + rr1) * 256 + k);
#pragma unroll
    for (int nn = 0; nn < 4; ++nn) {
      bf16x8 bv = ld8(W3p + (size_t)(nn * 16 + l16) * 256 + k);
      acc[0][nn] = MFMA(a0, bv, acc[0][nn]);
      acc[1][nn] = MFMA(a1, bv, acc[1][nn]);
    }
  }
  const int cr = (l >> 4) * 4;
#pragma unroll
  for (int m = 0; m < 2; ++m)
#pragma unroll
    for (int nn = 0; nn < 4; ++nn)
#pragma unroll
      for (int e = 0; e < 4; ++e) {
        const int col = nn * 16 + l16;
        gt[w * 32 + m * 16 + cr + e][col] =
            acc[m][nn][e] + (col < NOUT ? b3[col] : 0.f);
      }
  __syncthreads();
  if (tid < 128) {
    float mx = -INFINITY;
#pragma unroll
    for (int j = 0; j < NOUT; ++j) mx = fmaxf(mx, gt[tid][j]);
    float s = 0.f;
#pragma unroll
    for (int j = 0; j < NOUT; ++j) s += expf(gt[tid][j] - mx);
    lseb[tid] = logf(s) + mx;
  }
  __syncthreads();
  for (int idx = tid; idx < 128 * NOUT; idx += 256) {
    const int r = idx / NOUT, j = idx - r * NOUT;
    out[(size_t)(r0 + r) * NOUT + j] = gt[r][j] - lseb[r];
  }
}

// ---------------------------------------------------------------------------
// Prep kernels
// ---------------------------------------------------------------------------
__global__ void prep_w(const float* __restrict__ ih, const float* __restrict__ hh,
                       unsigned short* __restrict__ dst, int HU, int KI, int KH) {
  const int K = KI + KH;
  const long tot = (long)HU * 4 * K;
  for (long idx = (long)blockIdx.x * blockDim.x + threadIdx.x; idx < tot;
       idx += (long)gridDim.x * blockDim.x) {
    const int row = (int)(idx / K), k = (int)(idx % K);
    const int u = row >> 2, g = row & 3;
    const float v = (k < KI) ? ih[(size_t)(g * HU + u) * KI + k]
                             : hh[(size_t)(g * HU + u) * KH + (k - KI)];
    dst[idx] = f2bu(v);
  }
}

__global__ void prep_bias(const float* bih, const float* bhh, float* dst, int HU) {
  const int idx = blockIdx.x * blockDim.x + threadIdx.x;
  if (idx < 4 * HU) {
    const int u = idx >> 2, g = idx & 3;
    dst[idx] = bih[g * HU + u] + bhh[g * HU + u];
  }
}

__global__ void conv_bf(const float* __restrict__ src, unsigned short* __restrict__ dst,
                        long n) {
  for (long i = (long)blockIdx.x * blockDim.x + threadIdx.x; i < n;
       i += (long)gridDim.x * blockDim.x)
    dst[i] = f2bu(src[i]);
}

__global__ void prep_w3(const float* __restrict__ W3, unsigned short* __restrict__ dst) {
  const int i = blockIdx.x * blockDim.x + threadIdx.x;   // 64*256
  if (i < 64 * 256) {
    const int r = i >> 8;
    dst[i] = (r < NOUT) ? f2bu(W3[i]) : 0;
  }
}

__global__ void lengths_k(const int* x, int* len) {
  const int n = blockIdx.x * blockDim.x + threadIdx.x;
  if (n < NW) {
    int c = 0;
#pragma unroll
    for (int l = 0; l < LC; ++l) c += (x[(size_t)n * LC + l] != 0) ? 1 : 0;
    len[n] = c;
  }
}

__global__ void zero_k(int* p, int n) {
  const int i = blockIdx.x * blockDim.x + threadIdx.x;
  if (i < n) p[i] = 0;
}

__global__ void sentinel_k(float* out, int n) {
  const int i = blockIdx.x * blockDim.x + threadIdx.x;
  if (i < n) out[i] = 1000.0f;
}

// ---------------------------------------------------------------------------
extern "C" void kernel_launch(void* const* d_in, const int* in_sizes, int n_in,
                              void* d_out, int out_size, void* d_ws, size_t ws_size,
                              hipStream_t stream) {
  const int*   x     = (const int*)d_in[0];
  const float* emb   = (const float*)d_in[1];
  const float* cW_ih = (const float*)d_in[2];
  const float* cW_hh = (const float*)d_in[3];
  const float* cb_ih = (const float*)d_in[4];
  const float* cb_hh = (const float*)d_in[5];
  const float* fW_ih = (const float*)d_in[6];
  const float* fW_hh = (const float*)d_in[7];
  const float* fb_ih = (const float*)d_in[8];
  const float* fb_hh = (const float*)d_in[9];
  const float* bW_ih = (const float*)d_in[10];
  const float* bW_hh = (const float*)d_in[11];
  const float* bb_ih = (const float*)d_in[12];
  const float* bb_hh = (const float*)d_in[13];
  const float* W1 = (const float*)d_in[14];
  const float* b1 = (const float*)d_in[15];
  const float* W2 = (const float*)d_in[16];
  const float* b2 = (const float*)d_in[17];
  const float* W3 = (const float*)d_in[18];
  const float* b3 = (const float*)d_in[19];
  float* out = (float*)d_out;
  (void)in_sizes; (void)n_in;

  char* ws = (char*)d_ws;
  size_t off = 0;
  auto alloc = [&](size_t bytes) -> char* {
    char* p = ws + off;
    off += (bytes + 255) & ~(size_t)255;
    return p;
  };
  int*            len_  = (int*)alloc((size_t)NW * 4);
  int*            aflag = (int*)alloc((size_t)2 * SEQ * 32 * 4);
  unsigned short* embb  = (unsigned short*)alloc((size_t)100 * EDIM * 2);
  unsigned short* Wc_i  = (unsigned short*)alloc((size_t)1024 * 320 * 2);
  unsigned short* Wf_i  = (unsigned short*)alloc((size_t)2048 * 768 * 2);
  unsigned short* Wb_i  = (unsigned short*)alloc((size_t)2048 * 768 * 2);
  unsigned short* W1b   = (unsigned short*)alloc((size_t)256 * 1024 * 2);
  unsigned short* W2b   = (unsigned short*)alloc((size_t)256 * 256 * 2);
  unsigned short* W3p   = (unsigned short*)alloc((size_t)64 * 256 * 2);
  float*          bc_i  = (float*)alloc(1024 * 4);
  float*          bf_i  = (float*)alloc(2048 * 4);
  float*          bb_i  = (float*)alloc(2048 * 4);
  unsigned short* lastT = (unsigned short*)alloc((size_t)NW * HC * 2);       // 8MB
  unsigned short* hbL   = (unsigned short*)alloc((size_t)2 * 2 * 32 * 128 * 16 * 2);
  unsigned short* hsL   = (unsigned short*)alloc((size_t)2 * 32 * 128 * 128 * 16 * 2);
  unsigned short* h1    = (unsigned short*)alloc((size_t)NW * HC * 2);       // 8MB
  unsigned short* h2    = (unsigned short*)alloc((size_t)NW * HC * 2);       // 8MB

  if (off > ws_size) {
    sentinel_k<<<(out_size + 255) / 256, 256, 0, stream>>>(out, out_size);
    return;
  }

  auto cdiv = [](long a, long b) { return (int)((a + b - 1) / b); };

  // ---- prep ----
  prep_w<<<1280, 256, 0, stream>>>(cW_ih, cW_hh, Wc_i, HC, EDIM, HC);
  prep_w<<<3072, 256, 0, stream>>>(fW_ih, fW_hh, Wf_i, HW, HC, HW);
  prep_w<<<3072, 256, 0, stream>>>(bW_ih, bW_hh, Wb_i, HW, HC, HW);
  prep_bias<<<cdiv(1024, 256), 256, 0, stream>>>(cb_ih, cb_hh, bc_i, HC);
  prep_bias<<<cdiv(2048, 256), 256, 0, stream>>>(fb_ih, fb_hh, bf_i, HW);
  prep_bias<<<cdiv(2048, 256), 256, 0, stream>>>(bb_ih, bb_hh, bb_i, HW);
  conv_bf<<<25, 256, 0, stream>>>(emb, embb, 100L * EDIM);
  conv_bf<<<1024, 256, 0, stream>>>(W1, W1b, 256L * 1024);
  conv_bf<<<256, 256, 0, stream>>>(W2, W2b, 256L * 256);
  prep_w3<<<64, 256, 0, stream>>>(W3, W3p);
  lengths_k<<<cdiv(NW, 256), 256, 0, stream>>>(x, len_);
  zero_k<<<cdiv(2 * SEQ * 32, 256), 256, 0, stream>>>(aflag, 2 * SEQ * 32);

  // ---- persistent char LSTM (1 launch, r6 geometry) ----
  char_lstm<<<NW / 32, 256, 0, stream>>>(x, embb, Wc_i, bc_i, lastT, len_);

  // ---- persistent word BiLSTM (1 launch, flag barriers) ----
  word_lstm<<<NWB, 256, 0, stream>>>(lastT, Wf_i, Wb_i, bf_i, bb_i, hbL, hsL, aflag);

  // ---- MLP + fused logits/log_softmax ----
  mlp1_gemm<<<dim3(4, 128), 256, 0, stream>>>(hsL, W1b, b1, h1);
  mlp_gemm<<<dim3(4, 128), 256, 0, stream>>>(h1, 256, W2b, 256, b2, h2, 256, 8, 1);
  logits_fused<<<NW / 128, 256, 0, stream>>>(h2, W3p, b3, out);
}

// Round 9
// 3080.704 us; speedup vs baseline: 1.7279x; 1.1001x over previous
//
#include <hip/hip_runtime.h>
#include <hip/hip_bf16.h>
#include <math.h>

typedef __hip_bfloat16 bf16;
typedef __attribute__((ext_vector_type(8))) short bf16x8;   // 8 bf16 = 4 VGPR
typedef __attribute__((ext_vector_type(4))) float f32x4;

#define NW   16384
#define LC   20
#define EDIM 64
#define HC   256
#define HW   512
#define SEQ  128
#define NOUT 50
#define NWB  64      // word-kernel blocks (2 dirs x 32), must be co-resident

// ---- fast transcendentals (v_exp/v_rcp/v_log; ~1 ulp, fine vs bf16 eps) ----
#define LOG2E 1.4426950408889634f
__device__ __forceinline__ float fex2(float x) {
  float r; asm("v_exp_f32 %0, %1" : "=v"(r) : "v"(x)); return r;
}
__device__ __forceinline__ float frcp(float x) {
  float r; asm("v_rcp_f32 %0, %1" : "=v"(r) : "v"(x)); return r;
}
__device__ __forceinline__ float flog2(float x) {
  float r; asm("v_log_f32 %0, %1" : "=v"(r) : "v"(x)); return r;
}
__device__ __forceinline__ float fsig(float x) {          // 1/(1+e^-x)
  return frcp(1.f + fex2(-LOG2E * x));
}
__device__ __forceinline__ float ftanh(float x) {         // 1 - 2/(1+e^2x)
  return 1.f - 2.f * frcp(1.f + fex2(2.f * LOG2E * x));
}

__device__ __forceinline__ unsigned short f2bu(float f) {
  bf16 h = __float2bfloat16(f);
  return *reinterpret_cast<unsigned short*>(&h);
}
__device__ __forceinline__ bf16x8 ld8(const unsigned short* p) {
  return *reinterpret_cast<const bf16x8*>(p);
}
__device__ __forceinline__ bf16x8 ld8nt(const unsigned short* p) {   // stream, no L2 fill
  return __builtin_nontemporal_load(reinterpret_cast<const bf16x8*>(p));
}
__device__ __forceinline__ void st8nt(unsigned short* p, bf16x8 v) { // stream store
  __builtin_nontemporal_store(v, reinterpret_cast<bf16x8*>(p));
}
// Coherent (cross-XCD) plain 16B ops: sc0 sc1 -> bypass L1+L2, hit LLC.
__device__ __forceinline__ bf16x8 ld8sc(const unsigned short* p) {
  bf16x8 r;
  asm volatile("global_load_dwordx4 %0, %1, off sc0 sc1" : "=v"(r) : "v"(p));
  return r;
}
__device__ __forceinline__ void st8sc(unsigned short* p, bf16x8 v) {
  asm volatile("global_store_dwordx4 %0, %1, off sc0 sc1" :: "v"(p), "v"(v) : "memory");
}
#define MFMA(a, b, c) __builtin_amdgcn_mfma_f32_16x16x32_bf16(a, b, c, 0, 0, 0)

// ---------------------------------------------------------------------------
// Persistent char LSTM: 512 blocks x 32 words. h in LDS (double-buffered),
// c in registers. gt stride 65 (conflict-free update reads). Lane owns 8
// CONTIGUOUS units per chunk -> bf16x8 stores. lastT written nt (time-major).
// ---------------------------------------------------------------------------
__global__ __launch_bounds__(256) void char_lstm(
    const int* __restrict__ x, const unsigned short* __restrict__ embb,
    const unsigned short* __restrict__ Wc, const float* __restrict__ bc,
    unsigned short* __restrict__ lastT, const int* __restrict__ len) {
  __shared__ unsigned short Hs[2][32][264];   // 33.8 KB
  __shared__ float gt[4][32][65];             // 33.3 KB
  const int tid = threadIdx.x;
  const int w = tid >> 6, l = tid & 63;
  const int l16 = l & 15, lk8 = (l >> 4) * 8;
  const int hi = l >> 5;              // 0/1
  const int wl = l & 31;              // owned word (update phase)
  const int w0 = blockIdx.x * 32;
  const int mylen = len[w0 + wl];
  const int n = w0 + wl;
  const size_t lrow = (size_t)((n & 127) * 128 + (n >> 7)) * HC;  // time-major row
  float cst[4][8];
#pragma unroll
  for (int c = 0; c < 4; ++c)
#pragma unroll
    for (int i = 0; i < 8; ++i) cst[c][i] = 0.f;

  for (int t = 0; t < LC; ++t) {
    const int cur = t & 1, nxt = cur ^ 1;
    const int xi0 = x[(w0 + l16) * LC + t];
    const int xi1 = x[(w0 + 16 + l16) * LC + t];
#pragma unroll
    for (int c = 0; c < 4; ++c) {
      const int cc0 = w * 256 + c * 64;
      f32x4 acc[2][4] = {};
#pragma unroll
      for (int kk = 0; kk < 2; ++kk) {          // K 0..63: embedding
        const int k = kk * 32 + lk8;
        bf16x8 a0 = ld8(embb + (size_t)xi0 * EDIM + k);
        bf16x8 a1 = ld8(embb + (size_t)xi1 * EDIM + k);
        const unsigned short* wp = Wc + (size_t)(cc0 + l16) * 320 + k;
#pragma unroll
        for (int nn = 0; nn < 4; ++nn) {
          bf16x8 bv = ld8(wp + nn * 16 * 320);
          acc[0][nn] = MFMA(a0, bv, acc[0][nn]);
          acc[1][nn] = MFMA(a1, bv, acc[1][nn]);
        }
      }
      if (t > 0) {
#pragma unroll
        for (int kk = 2; kk < 10; ++kk) {       // K 64..319: h(t-1) from LDS
          const int k = kk * 32 + lk8;
          bf16x8 a0 = ld8(&Hs[cur][l16][k - 64]);
          bf16x8 a1 = ld8(&Hs[cur][16 + l16][k - 64]);
          const unsigned short* wp = Wc + (size_t)(cc0 + l16) * 320 + k;
#pragma unroll
          for (int nn = 0; nn < 4; ++nn) {
            bf16x8 bv = ld8(wp + nn * 16 * 320);
            acc[0][nn] = MFMA(a0, bv, acc[0][nn]);
            acc[1][nn] = MFMA(a1, bv, acc[1][nn]);
          }
        }
      }
      const int cr = (l >> 4) * 4;
#pragma unroll
      for (int m = 0; m < 2; ++m)
#pragma unroll
        for (int nn = 0; nn < 4; ++nn)
#pragma unroll
          for (int e = 0; e < 4; ++e)
            gt[w][m * 16 + cr + e][nn * 16 + l16] = acc[m][nn][e];
      // same-wave LDS RAW: compiler inserts lgkmcnt waits
      union { unsigned short s[8]; bf16x8 v; } hp;
#pragma unroll
      for (int i = 0; i < 8; ++i) {
        const int ul = hi * 8 + i;              // contiguous 8 units per lane
        const int col = 4 * ul;
        float gi = gt[w][wl][col + 0] + bc[cc0 + col + 0];
        float gf = gt[w][wl][col + 1] + bc[cc0 + col + 1];
        float gg = gt[w][wl][col + 2] + bc[cc0 + col + 2];
        float go = gt[w][wl][col + 3] + bc[cc0 + col + 3];
        float cc = fsig(gf) * cst[c][i] + fsig(gi) * ftanh(gg);
        cst[c][i] = cc;
        hp.s[i] = f2bu(fsig(go) * ftanh(cc));
      }
      const int ub16 = (cc0 >> 2) + hi * 8;     // unit base of this lane's 8
      *reinterpret_cast<bf16x8*>(&Hs[nxt][wl][ub16]) = hp.v;
      if (t == mylen - 1)
        st8nt(lastT + lrow + ub16, hp.v);
      else if (mylen == 0 && t == 0) {
        bf16x8 z = {};
        st8nt(lastT + lrow + ub16, z);
      }
    }
    __syncthreads();   // Hs[nxt] complete before next step reads it
  }
}

// ---------------------------------------------------------------------------
// Persistent word BiLSTM: 64 blocks (dir = bx>>5, 64 gate-cols each).
// lastT read nt (no L2 pollution -> weights stay resident), hsL written nt.
// h exchange via sc0sc1 16B ops; flag barrier overlapped with x-part MFMA.
// ---------------------------------------------------------------------------
__global__ __launch_bounds__(256, 1) void word_lstm(
    const unsigned short* __restrict__ lastT,   // [pos][128][HC]
    const unsigned short* __restrict__ Wf, const unsigned short* __restrict__ Wb,
    const float* __restrict__ bfi, const float* __restrict__ bbi,
    unsigned short* __restrict__ hbL,   // [2][2][32][128][16]
    unsigned short* __restrict__ hsL,   // [2][32][128][128][16]
    int* __restrict__ aflag) {          // [2][SEQ][32]
  __shared__ float gt[128][65];         // 33.3 KB
  const int tid = threadIdx.x;
  const int w = tid >> 6, l = tid & 63;
  const int l16 = l & 15, lk8 = (l >> 4) * 8;
  const int dir = blockIdx.x >> 5;
  const int nb = blockIdx.x & 31;
  const int c0 = nb * 64;               // gate-col base (of 2048)
  const unsigned short* W = dir ? Wb : Wf;
  const float* bias = dir ? bbi : bfi;
  const int ub = tid & 127;             // owned batch (update phase)
  const int uhi = tid >> 7;             // 0/1 -> units nb*16 + 8*uhi ..
  float cst[8];
#pragma unroll
  for (int i = 0; i < 8; ++i) cst[i] = 0.f;

  for (int t = 0; t < SEQ; ++t) {
    const int cur = t & 1;
    const int pos = dir ? (SEQ - 1 - t) : t;
    // ---- x-part: nt streamed lastT slab, independent of h ----
    f32x4 acc[2][4] = {};
#pragma unroll
    for (int kk = 0; kk < 8; ++kk) {
      const int k = kk * 32 + lk8;
      bf16x8 a0 = ld8nt(lastT + ((size_t)pos * 128 + w * 32 + l16) * HC + k);
      bf16x8 a1 = ld8nt(lastT + ((size_t)pos * 128 + w * 32 + l16 + 16) * HC + k);
      const unsigned short* wp = W + (size_t)(c0 + l16) * 768 + k;
#pragma unroll
      for (int nn = 0; nn < 4; ++nn) {
        bf16x8 bv = ld8(wp + nn * 16 * 768);
        acc[0][nn] = MFMA(a0, bv, acc[0][nn]);
        acc[1][nn] = MFMA(a1, bv, acc[1][nn]);
      }
    }
    if (t > 0) {
      // ---- flag-barrier wait for step t-1 (overlapped with x-part above) ----
      if (w == 0) {
        const int* fp = aflag + (dir * SEQ + (t - 1)) * 32;
        for (;;) {
          int v = 1;
          if (l < 32)
            v = __hip_atomic_load(fp + l, __ATOMIC_RELAXED,
                                  __HIP_MEMORY_SCOPE_AGENT);
          if (__ballot(v != 0) == ~0ull) break;
          __builtin_amdgcn_s_sleep(1);
        }
      }
      __syncthreads();
      // ---- h loads (coherent) + h-part MFMA ----
      bf16x8 af[16][2];
      const unsigned short* hp =
          hbL + (size_t)(((cur ^ 1) * 2 + dir) * 32) * 128 * 16;
#pragma unroll
      for (int kk = 0; kk < 16; ++kk) {
        const int u = kk * 32 + lk8;
        const int nbs = u >> 4, ul = u & 15;
#pragma unroll
        for (int r = 0; r < 2; ++r) {
          const int bt = w * 32 + l16 + r * 16;
          af[kk][r] = ld8sc(hp + ((size_t)nbs * 128 + bt) * 16 + ul);
        }
      }
      asm volatile("s_waitcnt vmcnt(0)" ::: "memory");
      __builtin_amdgcn_sched_barrier(0);   // rule #18: MFMA stays after wait
#pragma unroll
      for (int kk = 0; kk < 16; ++kk) {
        const int k = 256 + kk * 32 + lk8;
        const unsigned short* wp = W + (size_t)(c0 + l16) * 768 + k;
#pragma unroll
        for (int nn = 0; nn < 4; ++nn) {
          bf16x8 bv = ld8(wp + nn * 16 * 768);
          acc[0][nn] = MFMA(af[kk][0], bv, acc[0][nn]);
          acc[1][nn] = MFMA(af[kk][1], bv, acc[1][nn]);
        }
      }
    }
    const int cr = (l >> 4) * 4;
#pragma unroll
    for (int m = 0; m < 2; ++m)
#pragma unroll
      for (int nn = 0; nn < 4; ++nn)
#pragma unroll
        for (int e = 0; e < 4; ++e)
          gt[w * 32 + m * 16 + cr + e][nn * 16 + l16] = acc[m][nn][e];
    __syncthreads();
    union { unsigned short s[8]; bf16x8 v; } hv;
#pragma unroll
    for (int i = 0; i < 8; ++i) {
      const int ul = uhi * 8 + i;
      const int col = 4 * ul;
      float gi = gt[ub][col + 0] + bias[c0 + col + 0];
      float gf = gt[ub][col + 1] + bias[c0 + col + 1];
      float gg = gt[ub][col + 2] + bias[c0 + col + 2];
      float go = gt[ub][col + 3] + bias[c0 + col + 3];
      float cc = fsig(gf) * cst[i] + fsig(gi) * ftanh(gg);
      cst[i] = cc;
      hv.s[i] = f2bu(fsig(go) * ftanh(cc));
    }
    st8sc(hbL + (size_t)((cur * 2 + dir) * 32 + nb) * 128 * 16
              + (size_t)ub * 16 + uhi * 8, hv.v);
    st8nt(hsL + ((size_t)((dir * 32 + nb) * 128 + ub) * 128 + pos) * 16 + uhi * 8,
          hv.v);
    if (t < SEQ - 1) {
      asm volatile("s_waitcnt vmcnt(0)" ::: "memory");  // h at LLC
      __syncthreads();                                   // all waves drained
      if (tid == 0)
        __hip_atomic_store(aflag + (dir * SEQ + t) * 32 + nb, 1,
                           __ATOMIC_RELAXED, __HIP_MEMORY_SCOPE_AGENT);
    }
  }
}

// ---------------------------------------------------------------------------
// MLP layer 1: A gathered from hsL layout. out = relu(A @ W1^T + b1).
// ---------------------------------------------------------------------------
__global__ __launch_bounds__(256) void mlp1_gemm(
    const unsigned short* __restrict__ hsL, const unsigned short* __restrict__ W1b,
    const float* __restrict__ bias, unsigned short* __restrict__ out) {
  const int tid = threadIdx.x;
  const int w = tid >> 6, l = tid & 63;
  const int l16 = l & 15, lk8 = (l >> 4) * 8;
  const int row0 = blockIdx.y * 128 + w * 32;
  const int col0 = blockIdx.x * 64;
  f32x4 acc[2][4] = {};
  for (int kk = 0; kk < 32; ++kk) {
    const int k = kk * 32 + lk8;               // 0..1023
    const int dirk = k >> 9, u = k & 511, nbs = u >> 4, ul = u & 15;
    const int r0 = row0 + l16, r1 = r0 + 16;
    bf16x8 a0 = ld8(hsL + (((size_t)(dirk * 32 + nbs) * 128 + (r0 >> 7)) * 128
                           + (r0 & 127)) * 16 + ul);
    bf16x8 a1 = ld8(hsL + (((size_t)(dirk * 32 + nbs) * 128 + (r1 >> 7)) * 128
                           + (r1 & 127)) * 16 + ul);
    const unsigned short* wp = W1b + (size_t)(col0 + l16) * 1024 + k;
#pragma unroll
    for (int nn = 0; nn < 4; ++nn) {
      bf16x8 bv = ld8(wp + nn * 16 * 1024);
      acc[0][nn] = MFMA(a0, bv, acc[0][nn]);
      acc[1][nn] = MFMA(a1, bv, acc[1][nn]);
    }
  }
  const int cr = (l >> 4) * 4;
#pragma unroll
  for (int m = 0; m < 2; ++m)
#pragma unroll
    for (int nn = 0; nn < 4; ++nn)
#pragma unroll
      for (int e = 0; e < 4; ++e) {
        const int r = row0 + m * 16 + cr + e;
        const int c = col0 + nn * 16 + l16;
        out[(size_t)r * 256 + c] = f2bu(fmaxf(acc[m][nn][e] + bias[c], 0.f));
      }
}

// ---------------------------------------------------------------------------
// MLP layer 2 (row-major A): out = relu(A @ W2^T + b2).
// ---------------------------------------------------------------------------
__global__ __launch_bounds__(256) void mlp_gemm(
    const unsigned short* __restrict__ A, int lda,
    const unsigned short* __restrict__ W, int ldw,
    const float* __restrict__ bias, unsigned short* __restrict__ out,
    int ldo, int nk, int relu) {
  const int tid = threadIdx.x;
  const int w = tid >> 6, l = tid & 63;
  const int l16 = l & 15, lk8 = (l >> 4) * 8;
  const int row0 = blockIdx.y * 128 + w * 32;
  const int col0 = blockIdx.x * 64;
  f32x4 acc[2][4] = {};
  for (int kk = 0; kk < nk; ++kk) {
    const int k = kk * 32 + lk8;
    bf16x8 a0 = ld8(A + (size_t)(row0 + l16) * lda + k);
    bf16x8 a1 = ld8(A + (size_t)(row0 + 16 + l16) * lda + k);
    const unsigned short* wp = W + (size_t)(col0 + l16) * ldw + k;
    bf16x8 bb[4];
#pragma unroll
    for (int nn = 0; nn < 4; ++nn) bb[nn] = ld8(wp + nn * 16 * ldw);
#pragma unroll
    for (int nn = 0; nn < 4; ++nn) {
      acc[0][nn] = MFMA(a0, bb[nn], acc[0][nn]);
      acc[1][nn] = MFMA(a1, bb[nn], acc[1][nn]);
    }
  }
  const int cr = (l >> 4) * 4;
#pragma unroll
  for (int m = 0; m < 2; ++m)
#pragma unroll
    for (int nn = 0; nn < 4; ++nn)
#pragma unroll
      for (int e = 0; e < 4; ++e) {
        const int r = row0 + m * 16 + cr + e;
        const int c = col0 + nn * 16 + l16;
        float v = acc[m][nn][e] + bias[c];
        if (relu) v = fmaxf(v, 0.f);
        out[(size_t)r * ldo + c] = f2bu(v);
      }
}

// ---------------------------------------------------------------------------
// Logits (MFMA, N=64 padded) + log_softmax over 50, fused. 128 rows/block.
// ---------------------------------------------------------------------------
__global__ __launch_bounds__(256) void logits_fused(
    const unsigned short* __restrict__ h2, const unsigned short* __restrict__ W3p,
    const float* __restrict__ b3, float* __restrict__ out) {
  __shared__ float gt[128][68];
  __shared__ float lseb[128];
  const int tid = threadIdx.x;
  const int w = tid >> 6, l = tid & 63;
  const int l16 = l & 15, lk8 = (l >> 4) * 8;
  const int r0 = blockIdx.x * 128;
  const int rr0 = w * 32 + l16, rr1 = rr0 + 16;
  f32x4 acc[2][4] = {};
#pragma unroll
  for (int kk = 0; kk < 8; ++kk) {
    const int k = kk * 32 + lk8;
    bf16x8 a0 = ld8(h2 + (size_t)(r0 + rr0) * 256 + k);
    bf16x8 a1 = ld8(h2 + (size_t)(r0 + rr1) * 256 + k);
#pragma unroll
    for (int nn = 0; nn < 4; ++nn) {
      bf16x8 bv = ld8(W3p + (size_t)(nn * 16 + l16) * 256 + k);
      acc[0][nn] = MFMA(a0, bv, acc[0][nn]);
      acc[1][nn] = MFMA(a1, bv, acc[1][nn]);
    }
  }
  const int cr = (l >> 4) * 4;
#pragma unroll
  for (int m = 0; m < 2; ++m)
#pragma unroll
    for (int nn = 0; nn < 4; ++nn)
#pragma unroll
      for (int e = 0; e < 4; ++e) {
        const int col = nn * 16 + l16;
        gt[w * 32 + m * 16 + cr + e][col] =
            acc[m][nn][e] + (col < NOUT ? b3[col] : 0.f);
      }
  __syncthreads();
  if (tid < 128) {
    float mx = -INFINITY;
#pragma unroll
    for (int j = 0; j < NOUT; ++j) mx = fmaxf(mx, gt[tid][j]);
    float s = 0.f;
#pragma unroll
    for (int j = 0; j < NOUT; ++j) s += fex2(LOG2E * (gt[tid][j] - mx));
    lseb[tid] = flog2(s) * 0.6931471805599453f + mx;
  }
  __syncthreads();
  for (int idx = tid; idx < 128 * NOUT; idx += 256) {
    const int r = idx / NOUT, j = idx - r * NOUT;
    out[(size_t)(r0 + r) * NOUT + j] = gt[r][j] - lseb[r];
  }
}

// ---------------------------------------------------------------------------
// Prep kernels
// ---------------------------------------------------------------------------
__global__ void prep_w(const float* __restrict__ ih, const float* __restrict__ hh,
                       unsigned short* __restrict__ dst, int HU, int KI, int KH) {
  const int K = KI + KH;
  const long tot = (long)HU * 4 * K;
  for (long idx = (long)blockIdx.x * blockDim.x + threadIdx.x; idx < tot;
       idx += (long)gridDim.x * blockDim.x) {
    const int row = (int)(idx / K), k = (int)(idx % K);
    const int u = row >> 2, g = row & 3;
    const float v = (k < KI) ? ih[(size_t)(g * HU + u) * KI + k]
                             : hh[(size_t)(g * HU + u) * KH + (k - KI)];
    dst[idx] = f2bu(v);
  }
}

__global__ void prep_bias(const float* bih, const float* bhh, float* dst, int HU) {
  const int idx = blockIdx.x * blockDim.x + threadIdx.x;
  if (idx < 4 * HU) {
    const int u = idx >> 2, g = idx & 3;
    dst[idx] = bih[g * HU + u] + bhh[g * HU + u];
  }
}

__global__ void conv_bf(const float* __restrict__ src, unsigned short* __restrict__ dst,
                        long n) {
  for (long i = (long)blockIdx.x * blockDim.x + threadIdx.x; i < n;
       i += (long)gridDim.x * blockDim.x)
    dst[i] = f2bu(src[i]);
}

__global__ void prep_w3(const float* __restrict__ W3, unsigned short* __restrict__ dst) {
  const int i = blockIdx.x * blockDim.x + threadIdx.x;   // 64*256
  if (i < 64 * 256) {
    const int r = i >> 8;
    dst[i] = (r < NOUT) ? f2bu(W3[i]) : 0;
  }
}

__global__ void lengths_k(const int* x, int* len) {
  const int n = blockIdx.x * blockDim.x + threadIdx.x;
  if (n < NW) {
    int c = 0;
#pragma unroll
    for (int l = 0; l < LC; ++l) c += (x[(size_t)n * LC + l] != 0) ? 1 : 0;
    len[n] = c;
  }
}

__global__ void zero_k(int* p, int n) {
  const int i = blockIdx.x * blockDim.x + threadIdx.x;
  if (i < n) p[i] = 0;
}

__global__ void sentinel_k(float* out, int n) {
  const int i = blockIdx.x * blockDim.x + threadIdx.x;
  if (i < n) out[i] = 1000.0f;
}

// ---------------------------------------------------------------------------
extern "C" void kernel_launch(void* const* d_in, const int* in_sizes, int n_in,
                              void* d_out, int out_size, void* d_ws, size_t ws_size,
                              hipStream_t stream) {
  const int*   x     = (const int*)d_in[0];
  const float* emb   = (const float*)d_in[1];
  const float* cW_ih = (const float*)d_in[2];
  const float* cW_hh = (const float*)d_in[3];
  const float* cb_ih = (const float*)d_in[4];
  const float* cb_hh = (const float*)d_in[5];
  const float* fW_ih = (const float*)d_in[6];
  const float* fW_hh = (const float*)d_in[7];
  const float* fb_ih = (const float*)d_in[8];
  const float* fb_hh = (const float*)d_in[9];
  const float* bW_ih = (const float*)d_in[10];
  const float* bW_hh = (const float*)d_in[11];
  const float* bb_ih = (const float*)d_in[12];
  const float* bb_hh = (const float*)d_in[13];
  const float* W1 = (const float*)d_in[14];
  const float* b1 = (const float*)d_in[15];
  const float* W2 = (const float*)d_in[16];
  const float* b2 = (const float*)d_in[17];
  const float* W3 = (const float*)d_in[18];
  const float* b3 = (const float*)d_in[19];
  float* out = (float*)d_out;
  (void)in_sizes; (void)n_in;

  char* ws = (char*)d_ws;
  size_t off = 0;
  auto alloc = [&](size_t bytes) -> char* {
    char* p = ws + off;
    off += (bytes + 255) & ~(size_t)255;
    return p;
  };
  int*            len_  = (int*)alloc((size_t)NW * 4);
  int*            aflag = (int*)alloc((size_t)2 * SEQ * 32 * 4);
  unsigned short* embb  = (unsigned short*)alloc((size_t)100 * EDIM * 2);
  unsigned short* Wc_i  = (unsigned short*)alloc((size_t)1024 * 320 * 2);
  unsigned short* Wf_i  = (unsigned short*)alloc((size_t)2048 * 768 * 2);
  unsigned short* Wb_i  = (unsigned short*)alloc((size_t)2048 * 768 * 2);
  unsigned short* W1b   = (unsigned short*)alloc((size_t)256 * 1024 * 2);
  unsigned short* W2b   = (unsigned short*)alloc((size_t)256 * 256 * 2);
  unsigned short* W3p   = (unsigned short*)alloc((size_t)64 * 256 * 2);
  float*          bc_i  = (float*)alloc(1024 * 4);
  float*          bf_i  = (float*)alloc(2048 * 4);
  float*          bb_i  = (float*)alloc(2048 * 4);
  unsigned short* lastT = (unsigned short*)alloc((size_t)NW * HC * 2);       // 8MB
  unsigned short* hbL   = (unsigned short*)alloc((size_t)2 * 2 * 32 * 128 * 16 * 2);
  unsigned short* hsL   = (unsigned short*)alloc((size_t)2 * 32 * 128 * 128 * 16 * 2);
  unsigned short* h1    = (unsigned short*)alloc((size_t)NW * HC * 2);       // 8MB
  unsigned short* h2    = (unsigned short*)alloc((size_t)NW * HC * 2);       // 8MB

  if (off > ws_size) {
    sentinel_k<<<(out_size + 255) / 256, 256, 0, stream>>>(out, out_size);
    return;
  }

  auto cdiv = [](long a, long b) { return (int)((a + b - 1) / b); };

  // ---- prep ----
  prep_w<<<1280, 256, 0, stream>>>(cW_ih, cW_hh, Wc_i, HC, EDIM, HC);
  prep_w<<<3072, 256, 0, stream>>>(fW_ih, fW_hh, Wf_i, HW, HC, HW);
  prep_w<<<3072, 256, 0, stream>>>(bW_ih, bW_hh, Wb_i, HW, HC, HW);
  prep_bias<<<cdiv(1024, 256), 256, 0, stream>>>(cb_ih, cb_hh, bc_i, HC);
  prep_bias<<<cdiv(2048, 256), 256, 0, stream>>>(fb_ih, fb_hh, bf_i, HW);
  prep_bias<<<cdiv(2048, 256), 256, 0, stream>>>(bb_ih, bb_hh, bb_i, HW);
  conv_bf<<<25, 256, 0, stream>>>(emb, embb, 100L * EDIM);
  conv_bf<<<1024, 256, 0, stream>>>(W1, W1b, 256L * 1024);
  conv_bf<<<256, 256, 0, stream>>>(W2, W2b, 256L * 256);
  prep_w3<<<64, 256, 0, stream>>>(W3, W3p);
  lengths_k<<<cdiv(NW, 256), 256, 0, stream>>>(x, len_);
  zero_k<<<cdiv(2 * SEQ * 32, 256), 256, 0, stream>>>(aflag, 2 * SEQ * 32);

  // ---- persistent char LSTM (1 launch) ----
  char_lstm<<<NW / 32, 256, 0, stream>>>(x, embb, Wc_i, bc_i, lastT, len_);

  // ---- persistent word BiLSTM (1 launch, flag barriers) ----
  word_lstm<<<NWB, 256, 0, stream>>>(lastT, Wf_i, Wb_i, bf_i, bb_i, hbL, hsL, aflag);

  // ---- MLP + fused logits/log_softmax ----
  mlp1_gemm<<<dim3(4, 128), 256, 0, stream>>>(hsL, W1b, b1, h1);
  mlp_gemm<<<dim3(4, 128), 256, 0, stream>>>(h1, 256, W2b, 256, b2, h2, 256, 8, 1);
  logits_fused<<<NW / 128, 256, 0, stream>>>(h2, W3p, b3, out);
}

// Round 10
// 2761.384 us; speedup vs baseline: 1.9277x; 1.1156x over previous
//
#include <hip/hip_runtime.h>
#include <hip/hip_bf16.h>
#include <math.h>

typedef __hip_bfloat16 bf16;
typedef __attribute__((ext_vector_type(8))) short bf16x8;   // 8 bf16 = 4 VGPR
typedef __attribute__((ext_vector_type(4))) float f32x4;

#define NW   16384
#define LC   20
#define EDIM 64
#define HC   256
#define HW   512
#define SEQ  128
#define NOUT 50
#define NWB  64      // word-kernel blocks (2 dirs x 32), must be co-resident

// ---- fast transcendentals ----
#define LOG2E 1.4426950408889634f
__device__ __forceinline__ float fex2(float x) {
  float r; asm("v_exp_f32 %0, %1" : "=v"(r) : "v"(x)); return r;
}
__device__ __forceinline__ float frcp(float x) {
  float r; asm("v_rcp_f32 %0, %1" : "=v"(r) : "v"(x)); return r;
}
__device__ __forceinline__ float flog2(float x) {
  float r; asm("v_log_f32 %0, %1" : "=v"(r) : "v"(x)); return r;
}
__device__ __forceinline__ float fsig(float x) { return frcp(1.f + fex2(-LOG2E * x)); }
__device__ __forceinline__ float ftanh(float x) {
  return 1.f - 2.f * frcp(1.f + fex2(2.f * LOG2E * x));
}

__device__ __forceinline__ unsigned short f2bu(float f) {
  bf16 h = __float2bfloat16(f);
  return *reinterpret_cast<unsigned short*>(&h);
}
__device__ __forceinline__ bf16x8 ld8(const unsigned short* p) {
  return *reinterpret_cast<const bf16x8*>(p);
}
// Coherent (cross-XCD) plain 16B ops: sc0 sc1 -> bypass L1+L2, hit LLC.
__device__ __forceinline__ bf16x8 ld8sc(const unsigned short* p) {
  bf16x8 r;
  asm volatile("global_load_dwordx4 %0, %1, off sc0 sc1" : "=v"(r) : "v"(p));
  return r;
}
__device__ __forceinline__ void st8sc(unsigned short* p, bf16x8 v) {
  asm volatile("global_store_dwordx4 %0, %1, off sc0 sc1" :: "v"(p), "v"(v) : "memory");
}
#define MFMA(a, b, c) __builtin_amdgcn_mfma_f32_16x16x32_bf16(a, b, c, 0, 0, 0)

// ---------------------------------------------------------------------------
// Persistent char LSTM: 512 blocks x 32 words. Weights GATE-MAJOR interleaved
// (row (u>>4)*64 + g*16 + (u&15)) so lane l16's 4 B-frags = i,f,g,o of unit
// chunk*16+l16 -> LSTM update fully in-register (no gt LDS tile at all).
// h in LDS (double-buffered). lastT written once per word, time-major.
// ---------------------------------------------------------------------------
__global__ __launch_bounds__(256) void char_lstm(
    const int* __restrict__ x, const unsigned short* __restrict__ embb,
    const unsigned short* __restrict__ Wc, const float* __restrict__ bc,
    unsigned short* __restrict__ lastT, const int* __restrict__ len) {
  __shared__ unsigned short Hs[2][32][264];   // 33.8 KB only
  const int tid = threadIdx.x;
  const int w = tid >> 6, l = tid & 63;
  const int l16 = l & 15, lk8 = (l >> 4) * 8, q = l >> 4;
  const int w0 = blockIdx.x * 32;
  // lane owns 8 (word, unit-per-chunk) cells: word = q*4 + (j&3) + (j>>2)*16
  int lenj[8], lrow[8];
#pragma unroll
  for (int j = 0; j < 8; ++j) {
    const int wrd = q * 4 + (j & 3) + (j >> 2) * 16;
    const int n = w0 + wrd;
    lenj[j] = len[n];
    lrow[j] = ((n & 127) * 128 + (n >> 7)) * HC;   // time-major row base
  }
  float cst[4][8];
#pragma unroll
  for (int c = 0; c < 4; ++c)
#pragma unroll
    for (int j = 0; j < 8; ++j) cst[c][j] = 0.f;

  for (int t = 0; t < LC; ++t) {
    const int cur = t & 1, nxt = cur ^ 1;
    const int xi0 = x[(w0 + l16) * LC + t];
    const int xi1 = x[(w0 + 16 + l16) * LC + t];
#pragma unroll
    for (int c = 0; c < 4; ++c) {
      const int cc0 = w * 256 + c * 64;
      const int u = (w * 4 + c) * 16 + l16;     // this lane's unit this chunk
      f32x4 acc[2][4] = {};
#pragma unroll
      for (int kk = 0; kk < 2; ++kk) {          // K 0..63: embedding
        const int k = kk * 32 + lk8;
        bf16x8 a0 = ld8(embb + (size_t)xi0 * EDIM + k);
        bf16x8 a1 = ld8(embb + (size_t)xi1 * EDIM + k);
        const unsigned short* wp = Wc + (size_t)(cc0 + l16) * 320 + k;
#pragma unroll
        for (int nn = 0; nn < 4; ++nn) {
          bf16x8 bv = ld8(wp + nn * 16 * 320);
          acc[0][nn] = MFMA(a0, bv, acc[0][nn]);
          acc[1][nn] = MFMA(a1, bv, acc[1][nn]);
        }
      }
      if (t > 0) {
#pragma unroll
        for (int kk = 2; kk < 10; ++kk) {       // K 64..319: h(t-1) from LDS
          const int k = kk * 32 + lk8;
          bf16x8 a0 = ld8(&Hs[cur][l16][k - 64]);
          bf16x8 a1 = ld8(&Hs[cur][16 + l16][k - 64]);
          const unsigned short* wp = Wc + (size_t)(cc0 + l16) * 320 + k;
#pragma unroll
          for (int nn = 0; nn < 4; ++nn) {
            bf16x8 bv = ld8(wp + nn * 16 * 320);
            acc[0][nn] = MFMA(a0, bv, acc[0][nn]);
            acc[1][nn] = MFMA(a1, bv, acc[1][nn]);
          }
        }
      }
      const float b0 = bc[cc0 + 0 * 16 + l16];
      const float b1 = bc[cc0 + 1 * 16 + l16];
      const float b2 = bc[cc0 + 2 * 16 + l16];
      const float b3 = bc[cc0 + 3 * 16 + l16];
#pragma unroll
      for (int m = 0; m < 2; ++m)
#pragma unroll
        for (int e = 0; e < 4; ++e) {
          const int j = m * 4 + e;
          const float gi = acc[m][0][e] + b0;
          const float gf = acc[m][1][e] + b1;
          const float gg = acc[m][2][e] + b2;
          const float go = acc[m][3][e] + b3;
          const float ccv = fsig(gf) * cst[c][j] + fsig(gi) * ftanh(gg);
          cst[c][j] = ccv;
          const unsigned short h16 = f2bu(fsig(go) * ftanh(ccv));
          const int wrd = q * 4 + e + m * 16;
          Hs[nxt][wrd][u] = h16;
          if (t == lenj[j] - 1)          lastT[lrow[j] + u] = h16;
          else if (lenj[j] == 0 && t == 0) lastT[lrow[j] + u] = 0;  // bf16 +0
        }
    }
    __syncthreads();   // Hs[nxt] complete before next step reads it
  }
}

// ---------------------------------------------------------------------------
// Persistent word BiLSTM: 64 blocks (dir = bx>>5, 16 units each). Gate-major
// weights -> in-register update; 6KB LDS transpose for coalesced h writes.
// hsW[dir][nb][pos][128][16]: each block writes ONE contiguous 4KB slab per
// step (plain cached stores, L2 merges -> no RMW amplification).
// h exchange via sc0sc1; flag barrier overlapped with x-part MFMA.
// ---------------------------------------------------------------------------
__global__ __launch_bounds__(256, 1) void word_lstm(
    const unsigned short* __restrict__ lastT,   // [pos][128][HC]
    const unsigned short* __restrict__ Wf, const unsigned short* __restrict__ Wb,
    const float* __restrict__ bfi, const float* __restrict__ bbi,
    unsigned short* __restrict__ hbL,   // [2][2][32][128][16]
    unsigned short* __restrict__ hsW,   // [2][32][128 pos][128 b][16]
    int* __restrict__ aflag) {          // [2][SEQ][32]
  __shared__ unsigned short ht[128][24];        // 6 KB transpose buffer
  const int tid = threadIdx.x;
  const int w = tid >> 6, l = tid & 63;
  const int l16 = l & 15, lk8 = (l >> 4) * 8, q = l >> 4;
  const int dir = blockIdx.x >> 5;
  const int nb = blockIdx.x & 31;
  const int c0 = nb * 64;
  const unsigned short* W = dir ? Wb : Wf;
  const float* bias = dir ? bbi : bfi;
  const float b0 = bias[c0 + 0 * 16 + l16];
  const float b1 = bias[c0 + 1 * 16 + l16];
  const float b2 = bias[c0 + 2 * 16 + l16];
  const float b3 = bias[c0 + 3 * 16 + l16];
  float cst[8];
#pragma unroll
  for (int i = 0; i < 8; ++i) cst[i] = 0.f;

  for (int t = 0; t < SEQ; ++t) {
    const int cur = t & 1;
    const int pos = dir ? (SEQ - 1 - t) : t;
    // ---- x-part (independent of h; overlaps the flag wait below) ----
    f32x4 acc[2][4] = {};
#pragma unroll
    for (int kk = 0; kk < 8; ++kk) {
      const int k = kk * 32 + lk8;
      bf16x8 a0 = ld8(lastT + ((size_t)pos * 128 + w * 32 + l16) * HC + k);
      bf16x8 a1 = ld8(lastT + ((size_t)pos * 128 + w * 32 + l16 + 16) * HC + k);
      const unsigned short* wp = W + (size_t)(c0 + l16) * 768 + k;
#pragma unroll
      for (int nn = 0; nn < 4; ++nn) {
        bf16x8 bv = ld8(wp + nn * 16 * 768);
        acc[0][nn] = MFMA(a0, bv, acc[0][nn]);
        acc[1][nn] = MFMA(a1, bv, acc[1][nn]);
      }
    }
    if (t > 0) {
      if (w == 0) {                      // flag-barrier wait for step t-1
        const int* fp = aflag + (dir * SEQ + (t - 1)) * 32;
        for (;;) {
          int v = 1;
          if (l < 32)
            v = __hip_atomic_load(fp + l, __ATOMIC_RELAXED,
                                  __HIP_MEMORY_SCOPE_AGENT);
          if (__ballot(v != 0) == ~0ull) break;
          __builtin_amdgcn_s_sleep(1);
        }
      }
      __syncthreads();
      bf16x8 af[16][2];
      const unsigned short* hp =
          hbL + (size_t)(((cur ^ 1) * 2 + dir) * 32) * 128 * 16;
#pragma unroll
      for (int kk = 0; kk < 16; ++kk) {
        const int u = kk * 32 + lk8;
        const int nbs = u >> 4, ul = u & 15;
#pragma unroll
        for (int r = 0; r < 2; ++r) {
          const int bt = w * 32 + l16 + r * 16;
          af[kk][r] = ld8sc(hp + ((size_t)nbs * 128 + bt) * 16 + ul);
        }
      }
      asm volatile("s_waitcnt vmcnt(0)" ::: "memory");
      __builtin_amdgcn_sched_barrier(0);   // rule #18
#pragma unroll
      for (int kk = 0; kk < 16; ++kk) {
        const int k = 256 + kk * 32 + lk8;
        const unsigned short* wp = W + (size_t)(c0 + l16) * 768 + k;
#pragma unroll
        for (int nn = 0; nn < 4; ++nn) {
          bf16x8 bv = ld8(wp + nn * 16 * 768);
          acc[0][nn] = MFMA(af[kk][0], bv, acc[0][nn]);
          acc[1][nn] = MFMA(af[kk][1], bv, acc[1][nn]);
        }
      }
    }
    // ---- in-register LSTM update (lane owns unit nb*16+l16, 8 batches) ----
#pragma unroll
    for (int m = 0; m < 2; ++m)
#pragma unroll
      for (int e = 0; e < 4; ++e) {
        const int j = m * 4 + e;
        const float gi = acc[m][0][e] + b0;
        const float gf = acc[m][1][e] + b1;
        const float gg = acc[m][2][e] + b2;
        const float go = acc[m][3][e] + b3;
        const float ccv = fsig(gf) * cst[j] + fsig(gi) * ftanh(gg);
        cst[j] = ccv;
        const int bat = w * 32 + q * 4 + e + m * 16;    // 0..127
        ht[bat][l16] = f2bu(fsig(go) * ftanh(ccv));
      }
    __syncthreads();
    // ---- coalesced write-back: thread j covers bytes j*16 of the 4KB slab ----
    {
      const int ub = tid >> 1, uh = tid & 1;
      bf16x8 hv = ld8(&ht[ub][uh * 8]);
      st8sc(hbL + (size_t)((cur * 2 + dir) * 32 + nb) * 128 * 16
                + ub * 16 + uh * 8, hv);
      *reinterpret_cast<bf16x8*>(
          hsW + (((size_t)(dir * 32 + nb) * 128 + pos) * 128 + ub) * 16 + uh * 8) = hv;
    }
    if (t < SEQ - 1) {
      asm volatile("s_waitcnt vmcnt(0)" ::: "memory");
      __syncthreads();
      if (tid == 0)
        __hip_atomic_store(aflag + (dir * SEQ + t) * 32 + nb, 1,
                           __ATOMIC_RELAXED, __HIP_MEMORY_SCOPE_AGENT);
    }
  }
}

// ---------------------------------------------------------------------------
// MLP layer 1: A gathered from hsW layout. out = relu(A @ W1^T + b1).
// Row tile = one batch b (128 pos).
// ---------------------------------------------------------------------------
__global__ __launch_bounds__(256) void mlp1_gemm(
    const unsigned short* __restrict__ hsW, const unsigned short* __restrict__ W1b,
    const float* __restrict__ bias, unsigned short* __restrict__ out) {
  const int tid = threadIdx.x;
  const int w = tid >> 6, l = tid & 63;
  const int l16 = l & 15, lk8 = (l >> 4) * 8;
  const int by = blockIdx.y;                   // batch
  const int row0 = by * 128 + w * 32;
  const int col0 = blockIdx.x * 64;
  f32x4 acc[2][4] = {};
  for (int kk = 0; kk < 32; ++kk) {
    const int k = kk * 32 + lk8;               // 0..1023
    const int dirk = k >> 9, u = k & 511, nbs = u >> 4, ul = u & 15;
    const int p0 = w * 32 + l16, p1 = p0 + 16; // pos within batch
    bf16x8 a0 = ld8(hsW + (((size_t)(dirk * 32 + nbs) * 128 + p0) * 128 + by) * 16 + ul);
    bf16x8 a1 = ld8(hsW + (((size_t)(dirk * 32 + nbs) * 128 + p1) * 128 + by) * 16 + ul);
    const unsigned short* wp = W1b + (size_t)(col0 + l16) * 1024 + k;
#pragma unroll
    for (int nn = 0; nn < 4; ++nn) {
      bf16x8 bv = ld8(wp + nn * 16 * 1024);
      acc[0][nn] = MFMA(a0, bv, acc[0][nn]);
      acc[1][nn] = MFMA(a1, bv, acc[1][nn]);
    }
  }
  const int cr = (l >> 4) * 4;
#pragma unroll
  for (int m = 0; m < 2; ++m)
#pragma unroll
    for (int nn = 0; nn < 4; ++nn)
#pragma unroll
      for (int e = 0; e < 4; ++e) {
        const int r = row0 + m * 16 + cr + e;
        const int c = col0 + nn * 16 + l16;
        out[(size_t)r * 256 + c] = f2bu(fmaxf(acc[m][nn][e] + bias[c], 0.f));
      }
}

// ---------------------------------------------------------------------------
// MLP layer 2 (row-major A): out = relu(A @ W2^T + b2).
// ---------------------------------------------------------------------------
__global__ __launch_bounds__(256) void mlp_gemm(
    const unsigned short* __restrict__ A, int lda,
    const unsigned short* __restrict__ W, int ldw,
    const float* __restrict__ bias, unsigned short* __restrict__ out,
    int ldo, int nk, int relu) {
  const int tid = threadIdx.x;
  const int w = tid >> 6, l = tid & 63;
  const int l16 = l & 15, lk8 = (l >> 4) * 8;
  const int row0 = blockIdx.y * 128 + w * 32;
  const int col0 = blockIdx.x * 64;
  f32x4 acc[2][4] = {};
  for (int kk = 0; kk < nk; ++kk) {
    const int k = kk * 32 + lk8;
    bf16x8 a0 = ld8(A + (size_t)(row0 + l16) * lda + k);
    bf16x8 a1 = ld8(A + (size_t)(row0 + 16 + l16) * lda + k);
    const unsigned short* wp = W + (size_t)(col0 + l16) * ldw + k;
    bf16x8 bb[4];
#pragma unroll
    for (int nn = 0; nn < 4; ++nn) bb[nn] = ld8(wp + nn * 16 * ldw);
#pragma unroll
    for (int nn = 0; nn < 4; ++nn) {
      acc[0][nn] = MFMA(a0, bb[nn], acc[0][nn]);
      acc[1][nn] = MFMA(a1, bb[nn], acc[1][nn]);
    }
  }
  const int cr = (l >> 4) * 4;
#pragma unroll
  for (int m = 0; m < 2; ++m)
#pragma unroll
    for (int nn = 0; nn < 4; ++nn)
#pragma unroll
      for (int e = 0; e < 4; ++e) {
        const int r = row0 + m * 16 + cr + e;
        const int c = col0 + nn * 16 + l16;
        float v = acc[m][nn][e] + bias[c];
        if (relu) v = fmaxf(v, 0.f);
        out[(size_t)r * ldo + c] = f2bu(v);
      }
}

// ---------------------------------------------------------------------------
// Logits (MFMA, N=64 padded) + log_softmax over 50, fused. 128 rows/block.
// ---------------------------------------------------------------------------
__global__ __launch_bounds__(256) void logits_fused(
    const unsigned short* __restrict__ h2, const unsigned short* __restrict__ W3p,
    const float* __restrict__ b3, float* __restrict__ out) {
  __shared__ float gt[128][68];
  __shared__ float lseb[128];
  const int tid = threadIdx.x;
  const int w = tid >> 6, l = tid & 63;
  const int l16 = l & 15, lk8 = (l >> 4) * 8;
  const int r0 = blockIdx.x * 128;
  const int rr0 = w * 32 + l16, rr1 = rr0 + 16;
  f32x4 acc[2][4] = {};
#pragma unroll
  for (int kk = 0; kk < 8; ++kk) {
    const int k = kk * 32 + lk8;
    bf16x8 a0 = ld8(h2 + (size_t)(r0 + rr0) * 256 + k);
    bf16x8 a1 = ld8(h2 + (size_t)(r0 + rr1) * 256 + k);
#pragma unroll
    for (int nn = 0; nn < 4; ++nn) {
      bf16x8 bv = ld8(W3p + (size_t)(nn * 16 + l16) * 256 + k);
      acc[0][nn] = MFMA(a0, bv, acc[0][nn]);
      acc[1][nn] = MFMA(a1, bv, acc[1][nn]);
    }
  }
  const int cr = (l >> 4) * 4;
#pragma unroll
  for (int m = 0; m < 2; ++m)
#pragma unroll
    for (int nn = 0; nn < 4; ++nn)
#pragma unroll
      for (int e = 0; e < 4; ++e) {
        const int col = nn * 16 + l16;
        gt[w * 32 + m * 16 + cr + e][col] =
            acc[m][nn][e] + (col < NOUT ? b3[col] : 0.f);
      }
  __syncthreads();
  if (tid < 128) {
    float mx = -INFINITY;
#pragma unroll
    for (int j = 0; j < NOUT; ++j) mx = fmaxf(mx, gt[tid][j]);
    float s = 0.f;
#pragma unroll
    for (int j = 0; j < NOUT; ++j) s += fex2(LOG2E * (gt[tid][j] - mx));
    lseb[tid] = flog2(s) * 0.6931471805599453f + mx;
  }
  __syncthreads();
  for (int idx = tid; idx < 128 * NOUT; idx += 256) {
    const int r = idx / NOUT, j = idx - r * NOUT;
    out[(size_t)(r0 + r) * NOUT + j] = gt[r][j] - lseb[r];
  }
}

// ---------------------------------------------------------------------------
// Prep: GATE-MAJOR interleaved bf16 weights; new row = (u>>4)*64+g*16+(u&15).
// ---------------------------------------------------------------------------
__global__ void prep_w(const float* __restrict__ ih, const float* __restrict__ hh,
                       unsigned short* __restrict__ dst, int HU, int KI, int KH) {
  const int K = KI + KH;
  const long tot = (long)HU * 4 * K;
  for (long idx = (long)blockIdx.x * blockDim.x + threadIdx.x; idx < tot;
       idx += (long)gridDim.x * blockDim.x) {
    const int row = (int)(idx / K), k = (int)(idx % K);
    const int chunk = row >> 6, c = row & 63;
    const int g = c >> 4, u = chunk * 16 + (c & 15);
    const float v = (k < KI) ? ih[(size_t)(g * HU + u) * KI + k]
                             : hh[(size_t)(g * HU + u) * KH + (k - KI)];
    dst[idx] = f2bu(v);
  }
}

__global__ void prep_bias(const float* bih, const float* bhh, float* dst, int HU) {
  const int idx = blockIdx.x * blockDim.x + threadIdx.x;   // new-layout index
  if (idx < 4 * HU) {
    const int chunk = idx >> 6, c = idx & 63;
    const int g = c >> 4, u = chunk * 16 + (c & 15);
    dst[idx] = bih[g * HU + u] + bhh[g * HU + u];
  }
}

__global__ void conv_bf(const float* __restrict__ src, unsigned short* __restrict__ dst,
                        long n) {
  for (long i = (long)blockIdx.x * blockDim.x + threadIdx.x; i < n;
       i += (long)gridDim.x * blockDim.x)
    dst[i] = f2bu(src[i]);
}

__global__ void prep_w3(const float* __restrict__ W3, unsigned short* __restrict__ dst) {
  const int i = blockIdx.x * blockDim.x + threadIdx.x;   // 64*256
  if (i < 64 * 256) {
    const int r = i >> 8;
    dst[i] = (r < NOUT) ? f2bu(W3[i]) : 0;
  }
}

__global__ void lengths_k(const int* x, int* len) {
  const int n = blockIdx.x * blockDim.x + threadIdx.x;
  if (n < NW) {
    int c = 0;
#pragma unroll
    for (int l = 0; l < LC; ++l) c += (x[(size_t)n * LC + l] != 0) ? 1 : 0;
    len[n] = c;
  }
}

__global__ void zero_k(int* p, int n) {
  const int i = blockIdx.x * blockDim.x + threadIdx.x;
  if (i < n) p[i] = 0;
}

__global__ void sentinel_k(float* out, int n) {
  const int i = blockIdx.x * blockDim.x + threadIdx.x;
  if (i < n) out[i] = 1000.0f;
}

// ---------------------------------------------------------------------------
extern "C" void kernel_launch(void* const* d_in, const int* in_sizes, int n_in,
                              void* d_out, int out_size, void* d_ws, size_t ws_size,
                              hipStream_t stream) {
  const int*   x     = (const int*)d_in[0];
  const float* emb   = (const float*)d_in[1];
  const float* cW_ih = (const float*)d_in[2];
  const float* cW_hh = (const float*)d_in[3];
  const float* cb_ih = (const float*)d_in[4];
  const float* cb_hh = (const float*)d_in[5];
  const float* fW_ih = (const float*)d_in[6];
  const float* fW_hh = (const float*)d_in[7];
  const float* fb_ih = (const float*)d_in[8];
  const float* fb_hh = (const float*)d_in[9];
  const float* bW_ih = (const float*)d_in[10];
  const float* bW_hh = (const float*)d_in[11];
  const float* bb_ih = (const float*)d_in[12];
  const float* bb_hh = (const float*)d_in[13];
  const float* W1 = (const float*)d_in[14];
  const float* b1 = (const float*)d_in[15];
  const float* W2 = (const float*)d_in[16];
  const float* b2 = (const float*)d_in[17];
  const float* W3 = (const float*)d_in[18];
  const float* b3 = (const float*)d_in[19];
  float* out = (float*)d_out;
  (void)in_sizes; (void)n_in;

  char* ws = (char*)d_ws;
  size_t off = 0;
  auto alloc = [&](size_t bytes) -> char* {
    char* p = ws + off;
    off += (bytes + 255) & ~(size_t)255;
    return p;
  };
  int*            len_  = (int*)alloc((size_t)NW * 4);
  int*            aflag = (int*)alloc((size_t)2 * SEQ * 32 * 4);
  unsigned short* embb  = (unsigned short*)alloc((size_t)100 * EDIM * 2);
  unsigned short* Wc_i  = (unsigned short*)alloc((size_t)1024 * 320 * 2);
  unsigned short* Wf_i  = (unsigned short*)alloc((size_t)2048 * 768 * 2);
  unsigned short* Wb_i  = (unsigned short*)alloc((size_t)2048 * 768 * 2);
  unsigned short* W1b   = (unsigned short*)alloc((size_t)256 * 1024 * 2);
  unsigned short* W2b   = (unsigned short*)alloc((size_t)256 * 256 * 2);
  unsigned short* W3p   = (unsigned short*)alloc((size_t)64 * 256 * 2);
  float*          bc_i  = (float*)alloc(1024 * 4);
  float*          bf_i  = (float*)alloc(2048 * 4);
  float*          bb_i  = (float*)alloc(2048 * 4);
  unsigned short* lastT = (unsigned short*)alloc((size_t)NW * HC * 2);       // 8MB
  unsigned short* hbL   = (unsigned short*)alloc((size_t)2 * 2 * 32 * 128 * 16 * 2);
  unsigned short* hsW   = (unsigned short*)alloc((size_t)2 * 32 * 128 * 128 * 16 * 2);
  unsigned short* h1    = (unsigned short*)alloc((size_t)NW * HC * 2);       // 8MB
  unsigned short* h2    = (unsigned short*)alloc((size_t)NW * HC * 2);       // 8MB

  if (off > ws_size) {
    sentinel_k<<<(out_size + 255) / 256, 256, 0, stream>>>(out, out_size);
    return;
  }

  auto cdiv = [](long a, long b) { return (int)((a + b - 1) / b); };

  // ---- prep ----
  prep_w<<<1280, 256, 0, stream>>>(cW_ih, cW_hh, Wc_i, HC, EDIM, HC);
  prep_w<<<3072, 256, 0, stream>>>(fW_ih, fW_hh, Wf_i, HW, HC, HW);
  prep_w<<<3072, 256, 0, stream>>>(bW_ih, bW_hh, Wb_i, HW, HC, HW);
  prep_bias<<<cdiv(1024, 256), 256, 0, stream>>>(cb_ih, cb_hh, bc_i, HC);
  prep_bias<<<cdiv(2048, 256), 256, 0, stream>>>(fb_ih, fb_hh, bf_i, HW);
  prep_bias<<<cdiv(2048, 256), 256, 0, stream>>>(bb_ih, bb_hh, bb_i, HW);
  conv_bf<<<25, 256, 0, stream>>>(emb, embb, 100L * EDIM);
  conv_bf<<<1024, 256, 0, stream>>>(W1, W1b, 256L * 1024);
  conv_bf<<<256, 256, 0, stream>>>(W2, W2b, 256L * 256);
  prep_w3<<<64, 256, 0, stream>>>(W3, W3p);
  lengths_k<<<cdiv(NW, 256), 256, 0, stream>>>(x, len_);
  zero_k<<<cdiv(2 * SEQ * 32, 256), 256, 0, stream>>>(aflag, 2 * SEQ * 32);

  // ---- persistent char LSTM (1 launch) ----
  char_lstm<<<NW / 32, 256, 0, stream>>>(x, embb, Wc_i, bc_i, lastT, len_);

  // ---- persistent word BiLSTM (1 launch, flag barriers) ----
  word_lstm<<<NWB, 256, 0, stream>>>(lastT, Wf_i, Wb_i, bf_i, bb_i, hbL, hsW, aflag);

  // ---- MLP + fused logits/log_softmax ----
  mlp1_gemm<<<dim3(4, 128), 256, 0, stream>>>(hsW, W1b, b1, h1);
  mlp_gemm<<<dim3(4, 128), 256, 0, stream>>>(h1, 256, W2b, 256, b2, h2, 256, 8, 1);
  logits_fused<<<NW / 128, 256, 0, stream>>>(h2, W3p, b3, out);
}